// Round 1
// 461.899 us; speedup vs baseline: 1.2682x; 1.2682x over previous
//
#include <hip/hip_runtime.h>

typedef unsigned short u16;
typedef __attribute__((ext_vector_type(8))) short bf16x8;
typedef __attribute__((ext_vector_type(4))) float f32x4;

__device__ __forceinline__ float bf2f(u16 u) {
  union { unsigned int i; float f; } x; x.i = ((unsigned int)u) << 16; return x.f;
}
__device__ __forceinline__ u16 f2bf(float f) {
  union { float f; unsigned int i; } x; x.f = f;
  unsigned int r = x.i + 0x7fffu + ((x.i >> 16) & 1u);
  return (u16)(r >> 16);
}

// ---------------------------------------------------------------------------
// Merged pooling: one launch for 4 avg scales + maxpool.
// block = one output token (uniform decode, no divergence inside a block).
// ---------------------------------------------------------------------------
__global__ __launch_bounds__(256) void k_pool(
    const float* __restrict__ x, u16* __restrict__ pool)
{
  int blk = blockIdx.x;
  int b = blk / 1243;
  int tok = blk - b * 1243;
  int c = threadIdx.x;
  const float* xb = x + (size_t)b * 4096 * 512;
  float r0, r1;
  if (tok >= 987) {                       // maxpool 16x16, 4x4 windows
    int t = tok - 987;
    int oh = t >> 4, ow = t & 15;
    float m0 = -1e38f, m1 = -1e38f;
    for (int hh = 0; hh < 4; hh++)
      for (int ww = 0; ww < 4; ww++) {
        const float* px = xb + (size_t)((oh * 4 + hh) * 64 + ow * 4 + ww) * 512 + c;
        m0 = fmaxf(m0, px[0]);
        m1 = fmaxf(m1, px[256]);
      }
    r0 = m0; r1 = m1;
  } else {                                // adaptive avg, 4 scales
    int n, t;
    if (tok < 441)      { n = 21; t = tok; }
    else if (tok < 697) { n = 16; t = tok - 441; }
    else if (tok < 866) { n = 13; t = tok - 697; }
    else                { n = 11; t = tok - 866; }
    int oh = t / n, ow = t - oh * n;
    int h0 = (oh * 64) / n, h1 = ((oh + 1) * 64 + n - 1) / n;
    int w0 = (ow * 64) / n, w1 = ((ow + 1) * 64 + n - 1) / n;
    float inv = 1.0f / (float)((h1 - h0) * (w1 - w0));
    float s0 = 0.f, s1 = 0.f;
    for (int hh = h0; hh < h1; hh++)
      for (int ww = w0; ww < w1; ww++) {
        const float* px = xb + (size_t)(hh * 64 + ww) * 512 + c;
        s0 += px[0];
        s1 += px[256];
      }
    r0 = s0 * inv; r1 = s1 * inv;
  }
  u16* dst = pool + (size_t)(b * 1243 + tok) * 512 + c;
  dst[0]   = f2bf(r0);
  dst[256] = f2bf(r1);
}

// ---------------------------------------------------------------------------
// Merged weight transpose+convert: all 8 weight matrices in one launch.
// z: 0..4 = w_s1..w_s4,w_mx; 5 = Wq; 6 = Wkv (N=1024); 7 = Wp.
// dst layout (u16 units from wt_s): z*262144 for z<=5, then 6*262144, then +524288.
// ---------------------------------------------------------------------------
__global__ __launch_bounds__(256) void k_wt8(
    const float* w0, const float* w1, const float* w2, const float* w3,
    const float* w4, const float* w5, const float* w6, const float* w7,
    u16* __restrict__ wt_base)
{
  int z = blockIdx.z;
  int N = (z == 6) ? 1024 : 512;
  if (N == 512 && blockIdx.x >= 16) return;
  const float* W =
      z == 0 ? w0 : z == 1 ? w1 : z == 2 ? w2 : z == 3 ? w3 :
      z == 4 ? w4 : z == 5 ? w5 : z == 6 ? w6 : w7;
  size_t doff = (z <= 5) ? (size_t)z * 262144
                         : (z == 6 ? (size_t)6 * 262144 : (size_t)6 * 262144 + 524288);
  u16* Wt = wt_base + doff;

  __shared__ float tile[32][33];
  int n0 = blockIdx.x * 32, k0 = blockIdx.y * 32;
  int t = threadIdx.x;
  int rr = t >> 5, cc = t & 31;
#pragma unroll
  for (int ps = 0; ps < 4; ps++)
    tile[ps * 8 + rr][cc] = W[(size_t)(k0 + ps * 8 + rr) * N + n0 + cc];
  __syncthreads();
#pragma unroll
  for (int ps = 0; ps < 4; ps++)
    Wt[(size_t)(n0 + ps * 8 + rr) * 512 + k0 + cc] = f2bf(tile[cc][ps * 8 + rr]);
}

// f32 -> bf16 bulk convert (8 elems/thread)
__global__ __launch_bounds__(256) void k_f2b(
    const float* __restrict__ src, u16* __restrict__ dst)
{
  size_t i = ((size_t)blockIdx.x * 256 + threadIdx.x) * 8;
  float4 a = *(const float4*)(src + i);
  float4 b = *(const float4*)(src + i + 4);
  ushort4 u0, u1;
  u0.x = f2bf(a.x); u0.y = f2bf(a.y); u0.z = f2bf(a.z); u0.w = f2bf(a.w);
  u1.x = f2bf(b.x); u1.y = f2bf(b.y); u1.z = f2bf(b.z); u1.w = f2bf(b.w);
  *(ushort4*)(dst + i) = u0;
  *(ushort4*)(dst + i + 4) = u1;
}

// ---------------------------------------------------------------------------
// MFMA GEMM body: C[M][N] = A[M][K] @ Bt[N][K]^T (+bias +resid A). A,Bt bf16.
// 128x128 tile, BK=32, 4 waves (2x2), 4x4 mfma_f32_16x16x32_bf16 per wave.
// Shared between the generic wrapper and the segmented conv kernel.
// ---------------------------------------------------------------------------
__device__ __forceinline__ void gemm_body(
    const u16* __restrict__ Az, const u16* __restrict__ Bt,
    const float* __restrict__ bias, int resid,
    float* __restrict__ Cf, u16* __restrict__ Cb,
    int M, int N, int K, int m0, int n0)
{
  __shared__ __align__(16) u16 As[128][40];
  __shared__ __align__(16) u16 Bs[128][40];

  const int tid = threadIdx.x;
  const int lane = tid & 63, wv = tid >> 6;
  const int quad = lane >> 4, l15 = lane & 15;
  const int wm = (wv >> 1) * 64, wn = (wv & 1) * 64;

  f32x4 acc[4][4];
#pragma unroll
  for (int i = 0; i < 4; i++)
#pragma unroll
    for (int j = 0; j < 4; j++) acc[i][j] = (f32x4){0.f, 0.f, 0.f, 0.f};

  const int srow = tid >> 1;
  const int scol = (tid & 1) * 16;

  for (int k0 = 0; k0 < K; k0 += 32) {
    uint4 a0 = {0, 0, 0, 0}, a1 = {0, 0, 0, 0};
    if (m0 + srow < M) {
      const u16* ag = Az + (size_t)(m0 + srow) * K + k0 + scol;
      a0 = *(const uint4*)ag;
      a1 = *(const uint4*)(ag + 8);
    }
    const u16* bg = Bt + (size_t)(n0 + srow) * K + k0 + scol;
    uint4 b0 = *(const uint4*)bg;
    uint4 b1 = *(const uint4*)(bg + 8);
    __syncthreads();
    *(uint4*)&As[srow][scol]     = a0;
    *(uint4*)&As[srow][scol + 8] = a1;
    *(uint4*)&Bs[srow][scol]     = b0;
    *(uint4*)&Bs[srow][scol + 8] = b1;
    __syncthreads();

    bf16x8 af[4], bf[4];
#pragma unroll
    for (int i = 0; i < 4; i++)
      af[i] = *(const bf16x8*)&As[wm + i * 16 + l15][quad * 8];
#pragma unroll
    for (int j = 0; j < 4; j++)
      bf[j] = *(const bf16x8*)&Bs[wn + j * 16 + l15][quad * 8];
#pragma unroll
    for (int i = 0; i < 4; i++)
#pragma unroll
      for (int j = 0; j < 4; j++)
        acc[i][j] = __builtin_amdgcn_mfma_f32_16x16x32_bf16(af[i], bf[j], acc[i][j], 0, 0, 0);
  }

#pragma unroll
  for (int i = 0; i < 4; i++) {
    int rb = m0 + wm + i * 16 + quad * 4;
#pragma unroll
    for (int j = 0; j < 4; j++) {
      int col = n0 + wn + j * 16 + l15;
      float bv = bias ? bias[col] : 0.f;
#pragma unroll
      for (int r = 0; r < 4; r++) {
        int row = rb + r;
        if (row >= M) continue;
        float v = acc[i][j][r] + bv;
        if (resid) v += bf2f(Az[(size_t)row * K + col]);   // N == K when resid
        size_t oi = (size_t)row * N + col;
        if (Cb) Cb[oi] = f2bf(v);
        else    Cf[oi] = v;
      }
    }
  }
}

__global__ __launch_bounds__(256) void k_gemm_mfma(
    const u16* __restrict__ A, long long a_bs,
    const u16* __restrict__ Bt, const float* __restrict__ bias, int resid,
    float* __restrict__ Cf, u16* __restrict__ Cb, long long c_bs,
    int M, int N, int K)
{
  const int bz = blockIdx.z;
  gemm_body(A + (size_t)bz * a_bs, Bt, bias, resid,
            Cf ? Cf + (size_t)bz * c_bs : (float*)0,
            Cb ? Cb + (size_t)bz * c_bs : (u16*)0,
            M, N, K, blockIdx.y * 128, blockIdx.x * 128);
}

// Segmented conv GEMM: all 5 residual 1x1 convs in one launch.
// grid (4 n-blocks, 11 flat m-blocks, 8 batch). Flat y -> (segment, m0):
//  y 0-3: s1(441, 4 blocks); 4-5: s2(256); 6-7: s3(169); 8: s4(121); 9-10: mx(256)
__global__ __launch_bounds__(256) void k_conv_seg(
    const u16* __restrict__ pool, const u16* __restrict__ wts,
    const float* b0, const float* b1, const float* b2, const float* b3,
    const float* b4, u16* __restrict__ p)
{
  int y = blockIdx.y;
  int s, m0;
  if (y < 4)      { s = 0; m0 = y * 128; }
  else if (y < 6) { s = 1; m0 = (y - 4) * 128; }
  else if (y < 8) { s = 2; m0 = (y - 6) * 128; }
  else if (y < 9) { s = 3; m0 = 0; }
  else            { s = 4; m0 = (y - 9) * 128; }
  int t0  = s == 0 ? 0 : s == 1 ? 441 : s == 2 ? 697 : s == 3 ? 866 : 987;
  int cnt = s == 0 ? 441 : s == 1 ? 256 : s == 2 ? 169 : s == 3 ? 121 : 256;
  const float* bias = s == 0 ? b0 : s == 1 ? b1 : s == 2 ? b2 : s == 3 ? b3 : b4;
  size_t base = (size_t)blockIdx.z * (1243 * 512) + (size_t)t0 * 512;
  gemm_body(pool + base, wts + (size_t)s * 262144, bias, 1,
            (float*)0, p + base, cnt, 512, 512, m0, blockIdx.x * 128);
}

// ---------------------------------------------------------------------------
// LayerNorm in place over C=512 (bf16 p, f32 gamma/beta), one block per row
// ---------------------------------------------------------------------------
__global__ __launch_bounds__(256) void k_ln(
    u16* __restrict__ p, const float* __restrict__ g, const float* __restrict__ bb)
{
  __shared__ float red[8];
  size_t row = blockIdx.x;
  u16* pr = p + row * 512;
  int t = threadIdx.x;
  float v0 = bf2f(pr[t]), v1 = bf2f(pr[t + 256]);
  float s = v0 + v1;
#pragma unroll
  for (int off = 1; off < 64; off <<= 1) s += __shfl_xor(s, off);
  int wave = t >> 6;
  if ((t & 63) == 0) red[wave] = s;
  __syncthreads();
  float mean = (red[0] + red[1] + red[2] + red[3]) * (1.f / 512.f);
  float d0 = v0 - mean, d1 = v1 - mean;
  float s2 = d0 * d0 + d1 * d1;
#pragma unroll
  for (int off = 1; off < 64; off <<= 1) s2 += __shfl_xor(s2, off);
  if ((t & 63) == 0) red[4 + wave] = s2;
  __syncthreads();
  float var = (red[4] + red[5] + red[6] + red[7]) * (1.f / 512.f);
  float rstd = rsqrtf(var + 1e-5f);
  pr[t]       = f2bf(d0 * rstd * g[t]       + bb[t]);
  pr[t + 256] = f2bf(d1 * rstd * g[t + 256] + bb[t + 256]);
}

// ---------------------------------------------------------------------------
// mx output: p tokens [987..1243) [B][t][c] bf16 -> out2 [B][c][t] f32
// ---------------------------------------------------------------------------
__global__ __launch_bounds__(256) void k_mxout(
    const u16* __restrict__ p, float* __restrict__ out2)
{
  __shared__ float tile[64][65];
  int tt = blockIdx.x;
  int cc = blockIdx.y;
  int b  = blockIdx.z;
  int tid = threadIdx.x;
  for (int rep = 0; rep < 16; rep++) {
    int e = rep * 256 + tid;
    int r = e >> 6, c = e & 63;
    tile[r][c] = bf2f(p[((size_t)(b * 1243 + 987 + tt * 64 + r)) * 512 + cc * 64 + c]);
  }
  __syncthreads();
  for (int rep = 0; rep < 16; rep++) {
    int e = rep * 256 + tid;
    int crow = e >> 6, tpos = e & 63;
    out2[((size_t)(b * 512 + cc * 64 + crow)) * 256 + tt * 64 + tpos] = tile[tpos][crow];
  }
}

// ---------------------------------------------------------------------------
// MFMA flash attention v3.
// 2048 blocks (1D): bid>>6 = q-tile (32 queries), bid&63 = (h,b) -> all 32
// blocks sharing a KV head-slice land on one XCD (flat%8 invariant in qt).
// 4 waves: qw = wv>>1 picks 16 queries, kw = wv&1 picks a 32-key half of each
// 64-key tile. Max-free online softmax => cross-wave combine is a pure sum of
// partial (O, l) at the end. Tail keys: K/V zero-padded => e = exp2(0) = 1
// contributes only to l; subtract the constant 37 (=2304-2267) once.
// LDS = Ks+Vt (64x72) + Ps (32x72) = 23040 B -> 7 blocks/CU (grid feeds 8).
// ---------------------------------------------------------------------------
__global__ __launch_bounds__(256) void k_attn_mfma(
    const u16* __restrict__ qb, const u16* __restrict__ KV,
    u16* __restrict__ outb)
{
  __shared__ __align__(16) u16 Ks[64][72];  // [key][dim]
  __shared__ __align__(16) u16 Vt[64][72];  // [dim][key] (transposed)
  __shared__ __align__(16) u16 Ps[32][72];  // Q staging, then [query][key]

  const int bid = blockIdx.x;
  const int qt = bid >> 6;                  // 0..31
  const int hb = bid & 63;
  const int h = hb & 7, b = hb >> 3;
  const int tid = threadIdx.x;
  const int lane = tid & 63, wv = tid >> 6;
  const int qw = wv >> 1, kw = wv & 1;
  const int quad = lane >> 4, l15 = lane & 15;

  {  // stage Q (32 rows x 64 dims) through Ps
    int r = tid >> 3, c = (tid & 7) * 8;
    const u16* s = qb + (size_t)(b * 1024 + qt * 32 + r) * 512 + h * 64 + c;
    *(uint4*)&Ps[r][c] = *(const uint4*)s;
  }
  const u16* kvb = KV + (size_t)b * 2267 * 1024;

  const int kr = tid >> 2, kc = (tid & 3) * 16;  // K staging: key row, dim col
  const int vp = tid & 31, vc = (tid >> 5) * 8;  // V staging: key pair, dim octet

  float l_lane[4];
  f32x4 o_acc[4];
#pragma unroll
  for (int i = 0; i < 4; i++) { l_lane[i] = 0.f; o_acc[i] = (f32x4){0.f, 0.f, 0.f, 0.f}; }

  __syncthreads();
  // hoisted Q fragments (Ps reused for P afterwards; reads drain at the
  // first in-loop barrier, before any P write)
  bf16x8 aq0 = *(const bf16x8*)&Ps[qw * 16 + l15][quad * 8];
  bf16x8 aq1 = *(const bf16x8*)&Ps[qw * 16 + l15][32 + quad * 8];

  for (int n0 = 0; n0 < 2267; n0 += 64) {
    // ---- stage K (natural) + V (transposed via v_perm packs) ----
    uint4 k0v = {0, 0, 0, 0}, k1v = {0, 0, 0, 0};
    if (n0 + kr < 2267) {
      const u16* s = kvb + (size_t)(n0 + kr) * 1024 + h * 64 + kc;
      k0v = *(const uint4*)s;
      k1v = *(const uint4*)(s + 8);
    }
    uint4 va = {0, 0, 0, 0}, vbv = {0, 0, 0, 0};
    {
      int na = n0 + 2 * vp;
      const u16* s = kvb + (size_t)na * 1024 + 512 + h * 64 + vc;
      if (na < 2267)     va  = *(const uint4*)s;
      if (na + 1 < 2267) vbv = *(const uint4*)(s + 1024);
    }
    __syncthreads();   // previous iteration's readers done
    *(uint4*)&Ks[kr][kc]     = k0v;
    *(uint4*)&Ks[kr][kc + 8] = k1v;
    {
      const unsigned* pa = (const unsigned*)&va;
      const unsigned* pb = (const unsigned*)&vbv;
#pragma unroll
      for (int jd = 0; jd < 4; jd++) {
        unsigned lo = __builtin_amdgcn_perm(pb[jd], pa[jd], 0x05040100u);
        unsigned hi = __builtin_amdgcn_perm(pb[jd], pa[jd], 0x07060302u);
        *(unsigned*)&Vt[vc + 2 * jd][2 * vp]     = lo;
        *(unsigned*)&Vt[vc + 2 * jd + 1][2 * vp] = hi;
      }
    }
    __syncthreads();

    // ---- S = Q K^T over this wave's 32 keys ----
    f32x4 sacc[2];
#pragma unroll
    for (int t = 0; t < 2; t++) {
      int krow = kw * 32 + t * 16 + l15;
      bf16x8 bk0 = *(const bf16x8*)&Ks[krow][quad * 8];
      bf16x8 bk1 = *(const bf16x8*)&Ks[krow][32 + quad * 8];
      f32x4 z = (f32x4){0.f, 0.f, 0.f, 0.f};
      z = __builtin_amdgcn_mfma_f32_16x16x32_bf16(aq0, bk0, z, 0, 0, 0);
      sacc[t] = __builtin_amdgcn_mfma_f32_16x16x32_bf16(aq1, bk1, z, 0, 0, 0);
    }

    // ---- P = exp2(S*scale*log2e): 3 ops + 1 convert per score, no masking ----
#pragma unroll
    for (int r = 0; r < 4; r++) {
      float ls = 0.f;
#pragma unroll
      for (int t = 0; t < 2; t++) {
        float e = __builtin_amdgcn_exp2f(fminf(sacc[t][r] * 0.18033688f, 43.28f));
        ls += e;
        Ps[qw * 16 + quad * 4 + r][kw * 32 + t * 16 + l15] = f2bf(e);
      }
      l_lane[r] += ls;
    }

    // ---- O += P V (wave-local P: DS in-order, no barrier needed) ----
    bf16x8 ap = *(const bf16x8*)&Ps[qw * 16 + l15][kw * 32 + quad * 8];
#pragma unroll
    for (int t = 0; t < 4; t++) {
      bf16x8 vf = *(const bf16x8*)&Vt[t * 16 + l15][kw * 32 + quad * 8];
      o_acc[t] = __builtin_amdgcn_mfma_f32_16x16x32_bf16(ap, vf, o_acc[t], 0, 0, 0);
    }
  }

  // per-row l over this wave's keys (16-lane butterfly within each quad group)
  float lw[4];
#pragma unroll
  for (int r = 0; r < 4; r++) {
    float l = l_lane[r];
#pragma unroll
    for (int off = 1; off < 16; off <<= 1) l += __shfl_xor(l, off);
    lw[r] = l;
  }

  // cross-wave (kw) combine: partial O/l are pure sums (max-free softmax)
  __syncthreads();
  float* Op = (float*)&Ks[0][0];   // [32][64] f32 = 8192 B (fits in Ks)
  float* Lp = (float*)&Vt[0][0];   // [32] f32
  if (kw == 1) {
#pragma unroll
    for (int t = 0; t < 4; t++)
#pragma unroll
      for (int r = 0; r < 4; r++)
        Op[(qw * 16 + quad * 4 + r) * 64 + t * 16 + l15] = o_acc[t][r];
    if (l15 == 0) {
#pragma unroll
      for (int r = 0; r < 4; r++) Lp[qw * 16 + quad * 4 + r] = lw[r];
    }
  }
  __syncthreads();
  if (kw == 0) {
#pragma unroll
    for (int r = 0; r < 4; r++) {
      int row = qw * 16 + quad * 4 + r;
      float l = lw[r] + Lp[row] - 37.f;     // remove zero-pad tail contribution
      float inv = 1.f / fmaxf(l, 1e-20f);
#pragma unroll
      for (int t = 0; t < 4; t++) {
        size_t oi = (size_t)(b * 1024 + qt * 32 + row) * 512 + h * 64 + t * 16 + l15;
        outb[oi] = f2bf((o_acc[t][r] + Op[row * 64 + t * 16 + l15]) * inv);
      }
    }
  }
}

// ---------------------------------------------------------------------------
extern "C" void kernel_launch(void* const* d_in, const int* in_sizes, int n_in,
                              void* d_out, int out_size, void* d_ws, size_t ws_size,
                              hipStream_t stream)
{
  const float* x = (const float*)d_in[0];
  const float* m = (const float*)d_in[1];
  const float* ln_g = (const float*)d_in[12];
  const float* ln_b = (const float*)d_in[13];
  const float* Wq   = (const float*)d_in[14];
  const float* Wkv  = (const float*)d_in[15];
  const float* Wp   = (const float*)d_in[16];
  const float* bp   = (const float*)d_in[17];
  float* out = (float*)d_out;  // out f32 [8,1024,512] | mx f32 [8,512,256]

  // ws (u16 units): pool | p | q | KV | mb | weight-transposes   (~79 MB)
  u16* pool = (u16*)d_ws;
  u16* p    = pool + 5091328;
  u16* q    = p + 5091328;
  u16* KV   = q + 4194304;                 // 8*2267*1024
  u16* mb   = KV + 18571264;               // 8*1024*512
  u16* wt_s = mb + 4194304;                // 5 x 512x512 | wq | wkv | wp
  u16* attn_out = pool;                    // pool dead after conv GEMMs

  // weight prep (one launch) + m conversion
  k_wt8<<<dim3(32, 16, 8), 256, 0, stream>>>(
      (const float*)d_in[2], (const float*)d_in[4], (const float*)d_in[6],
      (const float*)d_in[8], (const float*)d_in[10], Wq, Wkv, Wp, wt_s);
  k_f2b<<<2048, 256, 0, stream>>>(m, mb);

  // pooling, one launch (tokens: s1[0,441) s2[441,697) s3[697,866) s4[866,987) mx[987,1243))
  k_pool<<<9944, 256, 0, stream>>>(x, pool);

  // residual 1x1 convs (MFMA), one segmented launch
  k_conv_seg<<<dim3(4, 11, 8), 256, 0, stream>>>(
      pool, wt_s, (const float*)d_in[3], (const float*)d_in[5],
      (const float*)d_in[7], (const float*)d_in[9], (const float*)d_in[11], p);

  k_mxout<<<dim3(4, 8, 8), 256, 0, stream>>>(p, out + 4194304);
  k_ln<<<9944, 256, 0, stream>>>(p, ln_g, ln_b);

  // q = m @ Wq -> bf16
  k_gemm_mfma<<<dim3(4, 8, 8), 256, 0, stream>>>(mb, (long long)1024 * 512,
                                                 wt_s + 5 * 262144, nullptr, 0,
                                                 nullptr, q, (long long)1024 * 512,
                                                 1024, 512, 512);
  // KV rows [0,1243) from LN(p)
  k_gemm_mfma<<<dim3(8, 10, 8), 256, 0, stream>>>(p, (long long)1243 * 512,
                                                  wt_s + 6 * 262144, nullptr, 0,
                                                  nullptr, KV, (long long)2267 * 1024,
                                                  1243, 1024, 512);
  // KV rows [1243,2267) from m
  k_gemm_mfma<<<dim3(8, 8, 8), 256, 0, stream>>>(mb, (long long)1024 * 512,
                                                 wt_s + 6 * 262144, nullptr, 0,
                                                 nullptr, KV + (size_t)1243 * 1024,
                                                 (long long)2267 * 1024,
                                                 1024, 1024, 512);

  // attention, all batches in one 1D launch (XCD-local KV decode)
  k_attn_mfma<<<2048, 256, 0, stream>>>(q, KV, attn_out);

  // out = attn_out @ Wp + bp -> f32 d_out
  k_gemm_mfma<<<dim3(4, 8, 8), 256, 0, stream>>>(attn_out, (long long)1024 * 512,
                                                 wt_s + 6 * 262144 + 524288, bp, 0,
                                                 out, nullptr, (long long)1024 * 512,
                                                 1024, 512, 512);
  (void)in_sizes; (void)n_in; (void)out_size; (void)ws_size;
}

// Round 2
// 412.354 us; speedup vs baseline: 1.4206x; 1.1202x over previous
//
#include <hip/hip_runtime.h>

typedef unsigned short u16;
typedef __attribute__((ext_vector_type(8))) short bf16x8;
typedef __attribute__((ext_vector_type(4))) float f32x4;

__device__ __forceinline__ float bf2f(u16 u) {
  union { unsigned int i; float f; } x; x.i = ((unsigned int)u) << 16; return x.f;
}
__device__ __forceinline__ u16 f2bf(float f) {
  union { float f; unsigned int i; } x; x.f = f;
  unsigned int r = x.i + 0x7fffu + ((x.i >> 16) & 1u);
  return (u16)(r >> 16);
}

// compiler-level memory fence (keeps LDS/global ops from crossing raw barriers)
#define CFENCE() asm volatile("" ::: "memory")

// ---------------------------------------------------------------------------
// Merged pooling: one launch for 4 avg scales + maxpool.
// ---------------------------------------------------------------------------
__global__ __launch_bounds__(256) void k_pool(
    const float* __restrict__ x, u16* __restrict__ pool)
{
  int blk = blockIdx.x;
  int b = blk / 1243;
  int tok = blk - b * 1243;
  int c = threadIdx.x;
  const float* xb = x + (size_t)b * 4096 * 512;
  float r0, r1;
  if (tok >= 987) {                       // maxpool 16x16, 4x4 windows
    int t = tok - 987;
    int oh = t >> 4, ow = t & 15;
    float m0 = -1e38f, m1 = -1e38f;
    for (int hh = 0; hh < 4; hh++)
      for (int ww = 0; ww < 4; ww++) {
        const float* px = xb + (size_t)((oh * 4 + hh) * 64 + ow * 4 + ww) * 512 + c;
        m0 = fmaxf(m0, px[0]);
        m1 = fmaxf(m1, px[256]);
      }
    r0 = m0; r1 = m1;
  } else {                                // adaptive avg, 4 scales
    int n, t;
    if (tok < 441)      { n = 21; t = tok; }
    else if (tok < 697) { n = 16; t = tok - 441; }
    else if (tok < 866) { n = 13; t = tok - 697; }
    else                { n = 11; t = tok - 866; }
    int oh = t / n, ow = t - oh * n;
    int h0 = (oh * 64) / n, h1 = ((oh + 1) * 64 + n - 1) / n;
    int w0 = (ow * 64) / n, w1 = ((ow + 1) * 64 + n - 1) / n;
    float inv = 1.0f / (float)((h1 - h0) * (w1 - w0));
    float s0 = 0.f, s1 = 0.f;
    for (int hh = h0; hh < h1; hh++)
      for (int ww = w0; ww < w1; ww++) {
        const float* px = xb + (size_t)(hh * 64 + ww) * 512 + c;
        s0 += px[0];
        s1 += px[256];
      }
    r0 = s0 * inv; r1 = s1 * inv;
  }
  u16* dst = pool + (size_t)(b * 1243 + tok) * 512 + c;
  dst[0]   = f2bf(r0);
  dst[256] = f2bf(r1);
}

// ---------------------------------------------------------------------------
// Merged weight transpose+convert: all 8 weight matrices in one launch.
// ---------------------------------------------------------------------------
__global__ __launch_bounds__(256) void k_wt8(
    const float* w0, const float* w1, const float* w2, const float* w3,
    const float* w4, const float* w5, const float* w6, const float* w7,
    u16* __restrict__ wt_base)
{
  int z = blockIdx.z;
  int N = (z == 6) ? 1024 : 512;
  if (N == 512 && blockIdx.x >= 16) return;
  const float* W =
      z == 0 ? w0 : z == 1 ? w1 : z == 2 ? w2 : z == 3 ? w3 :
      z == 4 ? w4 : z == 5 ? w5 : z == 6 ? w6 : w7;
  size_t doff = (z <= 5) ? (size_t)z * 262144
                         : (z == 6 ? (size_t)6 * 262144 : (size_t)6 * 262144 + 524288);
  u16* Wt = wt_base + doff;

  __shared__ float tile[32][33];
  int n0 = blockIdx.x * 32, k0 = blockIdx.y * 32;
  int t = threadIdx.x;
  int rr = t >> 5, cc = t & 31;
#pragma unroll
  for (int ps = 0; ps < 4; ps++)
    tile[ps * 8 + rr][cc] = W[(size_t)(k0 + ps * 8 + rr) * N + n0 + cc];
  __syncthreads();
#pragma unroll
  for (int ps = 0; ps < 4; ps++)
    Wt[(size_t)(n0 + ps * 8 + rr) * 512 + k0 + cc] = f2bf(tile[cc][ps * 8 + rr]);
}

// f32 -> bf16 bulk convert (8 elems/thread)
__global__ __launch_bounds__(256) void k_f2b(
    const float* __restrict__ src, u16* __restrict__ dst)
{
  size_t i = ((size_t)blockIdx.x * 256 + threadIdx.x) * 8;
  float4 a = *(const float4*)(src + i);
  float4 b = *(const float4*)(src + i + 4);
  ushort4 u0, u1;
  u0.x = f2bf(a.x); u0.y = f2bf(a.y); u0.z = f2bf(a.z); u0.w = f2bf(a.w);
  u1.x = f2bf(b.x); u1.y = f2bf(b.y); u1.z = f2bf(b.z); u1.w = f2bf(b.w);
  *(ushort4*)(dst + i) = u0;
  *(ushort4*)(dst + i + 4) = u1;
}

// ---------------------------------------------------------------------------
// Pipelined MFMA GEMM core: C = A[M][K] @ Bt[N][K]^T, templated epilogue.
// 128x128 tile, BK=32, 4 waves. 2-phase pipeline with raw barriers:
// loads for K-step k+1 stay in flight across the barrier (manual lgkmcnt(0)
// only -> no vmcnt drain), landing under step k's MFMA.
// ---------------------------------------------------------------------------
template <class EPI>
__device__ __forceinline__ void gemm_core(
    const u16* __restrict__ Az, const u16* __restrict__ Bt,
    int M, int K, int m0, int n0, EPI&& epi)
{
  __shared__ __align__(16) u16 As[128][40];
  __shared__ __align__(16) u16 Bs[128][40];

  const int tid = threadIdx.x;
  const int lane = tid & 63, wv = tid >> 6;
  const int quad = lane >> 4, l15 = lane & 15;
  const int wm = (wv >> 1) * 64, wn = (wv & 1) * 64;

  f32x4 acc[4][4];
#pragma unroll
  for (int i = 0; i < 4; i++)
#pragma unroll
    for (int j = 0; j < 4; j++) acc[i][j] = (f32x4){0.f, 0.f, 0.f, 0.f};

  const int srow = tid >> 1;
  const int scol = (tid & 1) * 16;
  const bool aok = (m0 + srow) < M;
  const u16* ag = Az + (size_t)(m0 + srow) * K + scol;
  const u16* bg = Bt + (size_t)(n0 + srow) * K + scol;

  uint4 a0 = {0, 0, 0, 0}, a1 = {0, 0, 0, 0}, b0, b1;
  if (aok) { a0 = *(const uint4*)ag; a1 = *(const uint4*)(ag + 8); }
  b0 = *(const uint4*)bg;
  b1 = *(const uint4*)(bg + 8);

  for (int k0 = 0; k0 < K; k0 += 32) {
    CFENCE();
    __builtin_amdgcn_s_barrier();                       // prev readers done
    asm volatile("s_waitcnt vmcnt(0)" ::: "memory");    // this tile's regs ready
    *(uint4*)&As[srow][scol]     = a0;
    *(uint4*)&As[srow][scol + 8] = a1;
    *(uint4*)&Bs[srow][scol]     = b0;
    *(uint4*)&Bs[srow][scol + 8] = b1;
    if (k0 + 32 < K) {                                  // prefetch next K-step
      if (aok) { a0 = *(const uint4*)(ag + k0 + 32); a1 = *(const uint4*)(ag + k0 + 40); }
      b0 = *(const uint4*)(bg + k0 + 32);
      b1 = *(const uint4*)(bg + k0 + 40);
    }
    asm volatile("s_waitcnt lgkmcnt(0)" ::: "memory");  // my ds_writes done (vmem stays in flight)
    __builtin_amdgcn_s_barrier();
    CFENCE();

    bf16x8 af[4];
#pragma unroll
    for (int i = 0; i < 4; i++)
      af[i] = *(const bf16x8*)&As[wm + i * 16 + l15][quad * 8];
#pragma unroll
    for (int j = 0; j < 4; j++) {
      bf16x8 bfj = *(const bf16x8*)&Bs[wn + j * 16 + l15][quad * 8];
#pragma unroll
      for (int i = 0; i < 4; i++)
        acc[i][j] = __builtin_amdgcn_mfma_f32_16x16x32_bf16(af[i], bfj, acc[i][j], 0, 0, 0);
    }
  }

#pragma unroll
  for (int i = 0; i < 4; i++) {
    int rb = m0 + wm + i * 16 + quad * 4;
#pragma unroll
    for (int j = 0; j < 4; j++) {
      int col = n0 + wn + j * 16 + l15;
#pragma unroll
      for (int r = 0; r < 4; r++) {
        int row = rb + r;
        if (row >= M) continue;
        epi(row, col, acc[i][j][r]);
      }
    }
  }
}

// bf16 output, no bias (KV from LN(p))
__global__ __launch_bounds__(256) void k_gemm_bf(
    const u16* __restrict__ A, long long a_bs, const u16* __restrict__ Bt,
    u16* __restrict__ C, long long c_bs, int M, int N, int K)
{
  const u16* Az = A + (size_t)blockIdx.z * a_bs;
  u16* Cz = C + (size_t)blockIdx.z * c_bs;
  gemm_core(Az, Bt, M, K, blockIdx.y * 128, blockIdx.x * 128,
            [&](int row, int col, float v) {
              Cz[(size_t)row * N + col] = f2bf(v);
            });
}

// f32 output + bias (final projection)
__global__ __launch_bounds__(256) void k_gemm_f32(
    const u16* __restrict__ A, long long a_bs, const u16* __restrict__ Bt,
    const float* __restrict__ bias, float* __restrict__ C, long long c_bs,
    int M, int N, int K)
{
  const u16* Az = A + (size_t)blockIdx.z * a_bs;
  float* Cz = C + (size_t)blockIdx.z * c_bs;
  gemm_core(Az, Bt, M, K, blockIdx.y * 128, blockIdx.x * 128,
            [&](int row, int col, float v) {
              Cz[(size_t)row * N + col] = v + bias[col];
            });
}

// merged q | KV-from-m GEMM: mb @ [Wq|Wkv] (N=1536), epilogue routes columns
__global__ __launch_bounds__(256) void k_gemm_qkv(
    const u16* __restrict__ mb, const u16* __restrict__ Bt,
    u16* __restrict__ q, u16* __restrict__ KV)
{
  int bz = blockIdx.z;
  const u16* Az = mb + (size_t)bz * (1024 * 512);
  u16* qz  = q  + (size_t)bz * (1024 * 512);
  u16* kvz = KV + (size_t)(bz * 2267 + 1243) * 1024;
  gemm_core(Az, Bt, 1024, 512, blockIdx.y * 128, blockIdx.x * 128,
            [&](int row, int col, float v) {
              u16 bv = f2bf(v);
              if (col < 512) qz[(size_t)row * 512 + col] = bv;
              else           kvz[(size_t)row * 1024 + (col - 512)] = bv;
            });
}

// Segmented conv GEMM: all 5 residual 1x1 convs in one launch.
__global__ __launch_bounds__(256) void k_conv_seg(
    const u16* __restrict__ pool, const u16* __restrict__ wts,
    const float* b0, const float* b1, const float* b2, const float* b3,
    const float* b4, u16* __restrict__ p)
{
  int y = blockIdx.y;
  int s, m0;
  if (y < 4)      { s = 0; m0 = y * 128; }
  else if (y < 6) { s = 1; m0 = (y - 4) * 128; }
  else if (y < 8) { s = 2; m0 = (y - 6) * 128; }
  else if (y < 9) { s = 3; m0 = 0; }
  else            { s = 4; m0 = (y - 9) * 128; }
  int t0  = s == 0 ? 0 : s == 1 ? 441 : s == 2 ? 697 : s == 3 ? 866 : 987;
  int cnt = s == 0 ? 441 : s == 1 ? 256 : s == 2 ? 169 : s == 3 ? 121 : 256;
  const float* bias = s == 0 ? b0 : s == 1 ? b1 : s == 2 ? b2 : s == 3 ? b3 : b4;
  size_t base = (size_t)blockIdx.z * (1243 * 512) + (size_t)t0 * 512;
  const u16* Az = pool + base;
  u16* Cz = p + base;
  gemm_core(Az, wts + (size_t)s * 262144, cnt, 512, m0, blockIdx.x * 128,
            [&](int row, int col, float v) {
              v += bias[col] + bf2f(Az[(size_t)row * 512 + col]);
              Cz[(size_t)row * 512 + col] = f2bf(v);
            });
}

// ---------------------------------------------------------------------------
// LayerNorm in place over C=512 (bf16 p, f32 gamma/beta), one block per row
// ---------------------------------------------------------------------------
__global__ __launch_bounds__(256) void k_ln(
    u16* __restrict__ p, const float* __restrict__ g, const float* __restrict__ bb)
{
  __shared__ float red[8];
  size_t row = blockIdx.x;
  u16* pr = p + row * 512;
  int t = threadIdx.x;
  float v0 = bf2f(pr[t]), v1 = bf2f(pr[t + 256]);
  float s = v0 + v1;
#pragma unroll
  for (int off = 1; off < 64; off <<= 1) s += __shfl_xor(s, off);
  int wave = t >> 6;
  if ((t & 63) == 0) red[wave] = s;
  __syncthreads();
  float mean = (red[0] + red[1] + red[2] + red[3]) * (1.f / 512.f);
  float d0 = v0 - mean, d1 = v1 - mean;
  float s2 = d0 * d0 + d1 * d1;
#pragma unroll
  for (int off = 1; off < 64; off <<= 1) s2 += __shfl_xor(s2, off);
  if ((t & 63) == 0) red[4 + wave] = s2;
  __syncthreads();
  float var = (red[4] + red[5] + red[6] + red[7]) * (1.f / 512.f);
  float rstd = rsqrtf(var + 1e-5f);
  pr[t]       = f2bf(d0 * rstd * g[t]       + bb[t]);
  pr[t + 256] = f2bf(d1 * rstd * g[t + 256] + bb[t + 256]);
}

// ---------------------------------------------------------------------------
// mx output: p tokens [987..1243) [B][t][c] bf16 -> out2 [B][c][t] f32
// ---------------------------------------------------------------------------
__global__ __launch_bounds__(256) void k_mxout(
    const u16* __restrict__ p, float* __restrict__ out2)
{
  __shared__ float tile[64][65];
  int tt = blockIdx.x;
  int cc = blockIdx.y;
  int b  = blockIdx.z;
  int tid = threadIdx.x;
  for (int rep = 0; rep < 16; rep++) {
    int e = rep * 256 + tid;
    int r = e >> 6, c = e & 63;
    tile[r][c] = bf2f(p[((size_t)(b * 1243 + 987 + tt * 64 + r)) * 512 + cc * 64 + c]);
  }
  __syncthreads();
  for (int rep = 0; rep < 16; rep++) {
    int e = rep * 256 + tid;
    int crow = e >> 6, tpos = e & 63;
    out2[((size_t)(b * 512 + cc * 64 + crow)) * 256 + tt * 64 + tpos] = tile[tpos][crow];
  }
}

// ---------------------------------------------------------------------------
// MFMA flash attention v4: 64 queries/block, 8 waves (qw 0..3 x kw 0..1),
// 2-phase pipelined K/V staging (loads for tile i+1 in flight under tile i's
// compute; raw barriers + manual lgkmcnt keep vmcnt from draining).
// Max-free softmax (exp2, zero-pad tail contributes exactly 1 per padded key
// to l -> subtract 37 once). Cross-wave (kw) combine is a pure sum.
// grid: 1024 blocks 1D; bid&63=(h,b) so KV-sharing blocks stay on one XCD.
// LDS 36864 B (Qs,Ks,Vt,Ps 64x72 each).
// ---------------------------------------------------------------------------
__global__ __launch_bounds__(512) void k_attn_mfma(
    const u16* __restrict__ qb, const u16* __restrict__ KV,
    u16* __restrict__ outb)
{
  __shared__ __align__(16) u16 smem[4][64][72];
#define Qs_ (smem[0])
#define Ks_ (smem[1])
#define Vt_ (smem[2])
#define Ps_ (smem[3])

  const int bid = blockIdx.x;
  const int qt = bid >> 6;                  // 0..15, 64 queries each
  const int hb = bid & 63;
  const int h = hb & 7, b = hb >> 3;
  const int tid = threadIdx.x;
  const int lane = tid & 63, wv = tid >> 6;
  const int qw = wv >> 1, kw = wv & 1;
  const int quad = lane >> 4, l15 = lane & 15;

  const u16* kvb = KV + (size_t)b * 2267 * 1024;
  const int kr = tid >> 3, kc = (tid & 7) * 8;   // K staging: 1 uint4/thread
  const int vp = tid & 31, vc = (tid >> 5) * 4;  // V staging: key pair x 4 dims

  uint4 kreg = {0, 0, 0, 0};
  uint2 vra = {0, 0}, vrb = {0, 0};
  auto load_tile = [&](int n0) {
    kreg = (uint4){0, 0, 0, 0};
    vra = (uint2){0, 0};
    vrb = (uint2){0, 0};
    if (n0 + kr < 2267)
      kreg = *(const uint4*)(kvb + (size_t)(n0 + kr) * 1024 + h * 64 + kc);
    int na = n0 + 2 * vp;
    const u16* s = kvb + (size_t)na * 1024 + 512 + h * 64 + vc;
    if (na < 2267)     vra = *(const uint2*)s;
    if (na + 1 < 2267) vrb = *(const uint2*)(s + 1024);
  };

  load_tile(0);                             // prefetch tile 0 first
  {                                         // stage Q (64 x 64) into Qs
    int r = tid >> 3, c = (tid & 7) * 8;
    *(uint4*)&Qs_[r][c] =
        *(const uint4*)(qb + (size_t)(b * 1024 + qt * 64 + r) * 512 + h * 64 + c);
  }

  float l_lane[4];
  f32x4 o_acc[4];
#pragma unroll
  for (int i = 0; i < 4; i++) { l_lane[i] = 0.f; o_acc[i] = (f32x4){0.f, 0.f, 0.f, 0.f}; }

  __syncthreads();                          // Q visible (drains tile-0 loads too)

  for (int n0 = 0; n0 < 2267; n0 += 64) {
    CFENCE();
    __builtin_amdgcn_s_barrier();                       // prev tile's readers done
    asm volatile("s_waitcnt vmcnt(0)" ::: "memory");    // this tile's regs ready
    *(uint4*)&Ks_[kr][kc] = kreg;
    {
      unsigned lo0 = __builtin_amdgcn_perm(vrb.x, vra.x, 0x05040100u);
      unsigned hi0 = __builtin_amdgcn_perm(vrb.x, vra.x, 0x07060302u);
      unsigned lo1 = __builtin_amdgcn_perm(vrb.y, vra.y, 0x05040100u);
      unsigned hi1 = __builtin_amdgcn_perm(vrb.y, vra.y, 0x07060302u);
      *(unsigned*)&Vt_[vc + 0][2 * vp] = lo0;
      *(unsigned*)&Vt_[vc + 1][2 * vp] = hi0;
      *(unsigned*)&Vt_[vc + 2][2 * vp] = lo1;
      *(unsigned*)&Vt_[vc + 3][2 * vp] = hi1;
    }
    if (n0 + 64 < 2267) load_tile(n0 + 64);             // prefetch next tile
    asm volatile("s_waitcnt lgkmcnt(0)" ::: "memory");  // ds_writes done; vmem in flight
    __builtin_amdgcn_s_barrier();
    CFENCE();

    // ---- S = Q K^T over this wave's 32 keys ----
    bf16x8 aq0 = *(const bf16x8*)&Qs_[qw * 16 + l15][quad * 8];
    bf16x8 aq1 = *(const bf16x8*)&Qs_[qw * 16 + l15][32 + quad * 8];
    f32x4 sacc[2];
#pragma unroll
    for (int t = 0; t < 2; t++) {
      int krow = kw * 32 + t * 16 + l15;
      bf16x8 bk0 = *(const bf16x8*)&Ks_[krow][quad * 8];
      bf16x8 bk1 = *(const bf16x8*)&Ks_[krow][32 + quad * 8];
      f32x4 z = (f32x4){0.f, 0.f, 0.f, 0.f};
      z = __builtin_amdgcn_mfma_f32_16x16x32_bf16(aq0, bk0, z, 0, 0, 0);
      sacc[t] = __builtin_amdgcn_mfma_f32_16x16x32_bf16(aq1, bk1, z, 0, 0, 0);
    }

    // ---- P = exp2(S * scale * log2e), no masking (zero-pad trick) ----
#pragma unroll
    for (int r = 0; r < 4; r++) {
      float ls = 0.f;
#pragma unroll
      for (int t = 0; t < 2; t++) {
        float e = __builtin_amdgcn_exp2f(fminf(sacc[t][r] * 0.18033688f, 43.28f));
        ls += e;
        Ps_[qw * 16 + quad * 4 + r][kw * 32 + t * 16 + l15] = f2bf(e);
      }
      l_lane[r] += ls;
    }

    // ---- O += P V (wave-local P region: rows qw*16.., cols kw*32..) ----
    bf16x8 ap = *(const bf16x8*)&Ps_[qw * 16 + l15][kw * 32 + quad * 8];
#pragma unroll
    for (int t = 0; t < 4; t++) {
      bf16x8 vf = *(const bf16x8*)&Vt_[t * 16 + l15][kw * 32 + quad * 8];
      o_acc[t] = __builtin_amdgcn_mfma_f32_16x16x32_bf16(ap, vf, o_acc[t], 0, 0, 0);
    }
  }

  // per-row l over this wave's keys (16-lane butterfly within quad groups)
  float lw[4];
#pragma unroll
  for (int r = 0; r < 4; r++) {
    float l = l_lane[r];
#pragma unroll
    for (int off = 1; off < 16; off <<= 1) l += __shfl_xor(l, off);
    lw[r] = l;
  }

  // cross-wave (kw) combine: pure sums (max-free softmax)
  __syncthreads();
  float* Op = (float*)&smem[0][0][0];   // 64x64 f32 = 16 KB (Qs+Ks region)
  float* Lp = (float*)&smem[2][0][0];   // 64 f32 (Vt region)
  if (kw == 1) {
#pragma unroll
    for (int t = 0; t < 4; t++)
#pragma unroll
      for (int r = 0; r < 4; r++)
        Op[(qw * 16 + quad * 4 + r) * 64 + t * 16 + l15] = o_acc[t][r];
    if (l15 == 0) {
#pragma unroll
      for (int r = 0; r < 4; r++) Lp[qw * 16 + quad * 4 + r] = lw[r];
    }
  }
  __syncthreads();
  if (kw == 0) {
#pragma unroll
    for (int r = 0; r < 4; r++) {
      int row = qw * 16 + quad * 4 + r;
      float l = lw[r] + Lp[row] - 37.f;     // remove zero-pad tail contribution
      float inv = 1.f / fmaxf(l, 1e-20f);
#pragma unroll
      for (int t = 0; t < 4; t++) {
        size_t oi = (size_t)(b * 1024 + qt * 64 + row) * 512 + h * 64 + t * 16 + l15;
        outb[oi] = f2bf((o_acc[t][r] + Op[row * 64 + t * 16 + l15]) * inv);
      }
    }
  }
#undef Qs_
#undef Ks_
#undef Vt_
#undef Ps_
}

// ---------------------------------------------------------------------------
extern "C" void kernel_launch(void* const* d_in, const int* in_sizes, int n_in,
                              void* d_out, int out_size, void* d_ws, size_t ws_size,
                              hipStream_t stream)
{
  const float* x = (const float*)d_in[0];
  const float* m = (const float*)d_in[1];
  const float* ln_g = (const float*)d_in[12];
  const float* ln_b = (const float*)d_in[13];
  const float* Wq   = (const float*)d_in[14];
  const float* Wkv  = (const float*)d_in[15];
  const float* Wp   = (const float*)d_in[16];
  const float* bp   = (const float*)d_in[17];
  float* out = (float*)d_out;  // out f32 [8,1024,512] | mx f32 [8,512,256]

  // ws (u16 units): pool | p | q | KV | mb | weight-transposes   (~79 MB)
  u16* pool = (u16*)d_ws;
  u16* p    = pool + 5091328;
  u16* q    = p + 5091328;
  u16* KV   = q + 4194304;                 // 8*2267*1024
  u16* mb   = KV + 18571264;               // 8*1024*512
  u16* wt_s = mb + 4194304;                // 5 x 512x512 | wq | wkv | wp
  u16* attn_out = pool;                    // pool dead after conv GEMMs

  // weight prep (one launch) + m conversion
  k_wt8<<<dim3(32, 16, 8), 256, 0, stream>>>(
      (const float*)d_in[2], (const float*)d_in[4], (const float*)d_in[6],
      (const float*)d_in[8], (const float*)d_in[10], Wq, Wkv, Wp, wt_s);
  k_f2b<<<2048, 256, 0, stream>>>(m, mb);

  // pooling, one launch
  k_pool<<<9944, 256, 0, stream>>>(x, pool);

  // residual 1x1 convs (MFMA), one segmented launch
  k_conv_seg<<<dim3(4, 11, 8), 256, 0, stream>>>(
      pool, wt_s, (const float*)d_in[3], (const float*)d_in[5],
      (const float*)d_in[7], (const float*)d_in[9], (const float*)d_in[11], p);

  k_mxout<<<dim3(4, 8, 8), 256, 0, stream>>>(p, out + 4194304);
  k_ln<<<9944, 256, 0, stream>>>(p, ln_g, ln_b);

  // q | KV rows [1243,2267) from m, one merged GEMM (Wq^T and Wkv^T contiguous)
  k_gemm_qkv<<<dim3(12, 8, 8), 256, 0, stream>>>(mb, wt_s + 5 * 262144, q, KV);

  // KV rows [0,1243) from LN(p)
  k_gemm_bf<<<dim3(8, 10, 8), 256, 0, stream>>>(p, (long long)1243 * 512,
                                                wt_s + 6 * 262144,
                                                KV, (long long)2267 * 1024,
                                                1243, 1024, 512);

  // attention, all batches in one 1D launch (XCD-local KV decode)
  k_attn_mfma<<<1024, 512, 0, stream>>>(q, KV, attn_out);

  // out = attn_out @ Wp + bp -> f32 d_out
  k_gemm_f32<<<dim3(4, 8, 8), 256, 0, stream>>>(attn_out, (long long)1024 * 512,
                                                wt_s + 6 * 262144 + 524288, bp,
                                                out, (long long)1024 * 512,
                                                1024, 512, 512);
  (void)in_sizes; (void)n_in; (void)out_size; (void)ws_size;
}

// Round 3
// 409.314 us; speedup vs baseline: 1.4312x; 1.0074x over previous
//
#include <hip/hip_runtime.h>

typedef unsigned short u16;
typedef __attribute__((ext_vector_type(8))) short bf16x8;
typedef __attribute__((ext_vector_type(4))) float f32x4;

__device__ __forceinline__ float bf2f(u16 u) {
  union { unsigned int i; float f; } x; x.i = ((unsigned int)u) << 16; return x.f;
}
__device__ __forceinline__ u16 f2bf(float f) {
  union { float f; unsigned int i; } x; x.f = f;
  unsigned int r = x.i + 0x7fffu + ((x.i >> 16) & 1u);
  return (u16)(r >> 16);
}

#define CFENCE() asm volatile("" ::: "memory")

// quad_perm DPP helpers (VALU-pipe lane exchange within groups of 4)
__device__ __forceinline__ float qpB1(float v) {   // lanes [1,0,3,2]  (xor 1)
  return __builtin_bit_cast(float, __builtin_amdgcn_update_dpp(
      0, __builtin_bit_cast(int, v), 0xB1, 0xF, 0xF, true));
}
__device__ __forceinline__ float qp4E(float v) {   // lanes [2,3,0,1]  (xor 2)
  return __builtin_bit_cast(float, __builtin_amdgcn_update_dpp(
      0, __builtin_bit_cast(int, v), 0x4E, 0xF, 0xF, true));
}
__device__ __forceinline__ unsigned cvtpk_bf16(float lo, float hi) {
  unsigned r;
  asm("v_cvt_pk_bf16_f32 %0, %1, %2" : "=v"(r) : "v"(lo), "v"(hi));
  return r;
}

// ---------------------------------------------------------------------------
// Merged pooling + m f32->bf16 convert. Blocks [0,9944): pool; rest: convert.
// ---------------------------------------------------------------------------
__global__ __launch_bounds__(256) void k_pool(
    const float* __restrict__ x, u16* __restrict__ pool,
    const float* __restrict__ m, u16* __restrict__ mb)
{
  int blk = blockIdx.x;
  if (blk >= 9944) {                      // f2b segment (m -> mb)
    size_t i = ((size_t)(blk - 9944) * 256 + threadIdx.x) * 8;
    float4 a = *(const float4*)(m + i);
    float4 b = *(const float4*)(m + i + 4);
    ushort4 u0, u1;
    u0.x = f2bf(a.x); u0.y = f2bf(a.y); u0.z = f2bf(a.z); u0.w = f2bf(a.w);
    u1.x = f2bf(b.x); u1.y = f2bf(b.y); u1.z = f2bf(b.z); u1.w = f2bf(b.w);
    *(ushort4*)(mb + i) = u0;
    *(ushort4*)(mb + i + 4) = u1;
    return;
  }
  int b = blk / 1243;
  int tok = blk - b * 1243;
  int c = threadIdx.x;
  const float* xb = x + (size_t)b * 4096 * 512;
  float r0, r1;
  if (tok >= 987) {                       // maxpool 16x16, 4x4 windows
    int t = tok - 987;
    int oh = t >> 4, ow = t & 15;
    float m0 = -1e38f, m1 = -1e38f;
    for (int hh = 0; hh < 4; hh++)
      for (int ww = 0; ww < 4; ww++) {
        const float* px = xb + (size_t)((oh * 4 + hh) * 64 + ow * 4 + ww) * 512 + c;
        m0 = fmaxf(m0, px[0]);
        m1 = fmaxf(m1, px[256]);
      }
    r0 = m0; r1 = m1;
  } else {                                // adaptive avg, 4 scales
    int n, t;
    if (tok < 441)      { n = 21; t = tok; }
    else if (tok < 697) { n = 16; t = tok - 441; }
    else if (tok < 866) { n = 13; t = tok - 697; }
    else                { n = 11; t = tok - 866; }
    int oh = t / n, ow = t - oh * n;
    int h0 = (oh * 64) / n, h1 = ((oh + 1) * 64 + n - 1) / n;
    int w0 = (ow * 64) / n, w1 = ((ow + 1) * 64 + n - 1) / n;
    float inv = 1.0f / (float)((h1 - h0) * (w1 - w0));
    float s0 = 0.f, s1 = 0.f;
    for (int hh = h0; hh < h1; hh++)
      for (int ww = w0; ww < w1; ww++) {
        const float* px = xb + (size_t)(hh * 64 + ww) * 512 + c;
        s0 += px[0];
        s1 += px[256];
      }
    r0 = s0 * inv; r1 = s1 * inv;
  }
  u16* dst = pool + (size_t)(b * 1243 + tok) * 512 + c;
  dst[0]   = f2bf(r0);
  dst[256] = f2bf(r1);
}

// ---------------------------------------------------------------------------
// Merged weight transpose+convert: all 8 weight matrices in one launch.
// ---------------------------------------------------------------------------
__global__ __launch_bounds__(256) void k_wt8(
    const float* w0, const float* w1, const float* w2, const float* w3,
    const float* w4, const float* w5, const float* w6, const float* w7,
    u16* __restrict__ wt_base)
{
  int z = blockIdx.z;
  int N = (z == 6) ? 1024 : 512;
  if (N == 512 && blockIdx.x >= 16) return;
  const float* W =
      z == 0 ? w0 : z == 1 ? w1 : z == 2 ? w2 : z == 3 ? w3 :
      z == 4 ? w4 : z == 5 ? w5 : z == 6 ? w6 : w7;
  size_t doff = (z <= 5) ? (size_t)z * 262144
                         : (z == 6 ? (size_t)6 * 262144 : (size_t)6 * 262144 + 524288);
  u16* Wt = wt_base + doff;

  __shared__ float tile[32][33];
  int n0 = blockIdx.x * 32, k0 = blockIdx.y * 32;
  int t = threadIdx.x;
  int rr = t >> 5, cc = t & 31;
#pragma unroll
  for (int ps = 0; ps < 4; ps++)
    tile[ps * 8 + rr][cc] = W[(size_t)(k0 + ps * 8 + rr) * N + n0 + cc];
  __syncthreads();
#pragma unroll
  for (int ps = 0; ps < 4; ps++)
    Wt[(size_t)(n0 + ps * 8 + rr) * 512 + k0 + cc] = f2bf(tile[cc][ps * 8 + rr]);
}

// ---------------------------------------------------------------------------
// Pipelined MFMA GEMM core (128x128, BK=32, 4 waves, 2-phase, raw barriers)
// ---------------------------------------------------------------------------
template <class EPI>
__device__ __forceinline__ void gemm_core(
    const u16* __restrict__ Az, const u16* __restrict__ Bt,
    int M, int K, int m0, int n0, EPI&& epi)
{
  __shared__ __align__(16) u16 As[128][40];
  __shared__ __align__(16) u16 Bs[128][40];

  const int tid = threadIdx.x;
  const int lane = tid & 63, wv = tid >> 6;
  const int quad = lane >> 4, l15 = lane & 15;
  const int wm = (wv >> 1) * 64, wn = (wv & 1) * 64;

  f32x4 acc[4][4];
#pragma unroll
  for (int i = 0; i < 4; i++)
#pragma unroll
    for (int j = 0; j < 4; j++) acc[i][j] = (f32x4){0.f, 0.f, 0.f, 0.f};

  const int srow = tid >> 1;
  const int scol = (tid & 1) * 16;
  const bool aok = (m0 + srow) < M;
  const u16* ag = Az + (size_t)(m0 + srow) * K + scol;
  const u16* bg = Bt + (size_t)(n0 + srow) * K + scol;

  uint4 a0 = {0, 0, 0, 0}, a1 = {0, 0, 0, 0}, b0, b1;
  if (aok) { a0 = *(const uint4*)ag; a1 = *(const uint4*)(ag + 8); }
  b0 = *(const uint4*)bg;
  b1 = *(const uint4*)(bg + 8);

  for (int k0 = 0; k0 < K; k0 += 32) {
    CFENCE();
    __builtin_amdgcn_s_barrier();
    asm volatile("s_waitcnt vmcnt(0)" ::: "memory");
    *(uint4*)&As[srow][scol]     = a0;
    *(uint4*)&As[srow][scol + 8] = a1;
    *(uint4*)&Bs[srow][scol]     = b0;
    *(uint4*)&Bs[srow][scol + 8] = b1;
    if (k0 + 32 < K) {
      if (aok) { a0 = *(const uint4*)(ag + k0 + 32); a1 = *(const uint4*)(ag + k0 + 40); }
      b0 = *(const uint4*)(bg + k0 + 32);
      b1 = *(const uint4*)(bg + k0 + 40);
    }
    asm volatile("s_waitcnt lgkmcnt(0)" ::: "memory");
    __builtin_amdgcn_s_barrier();
    CFENCE();

    bf16x8 af[4];
#pragma unroll
    for (int i = 0; i < 4; i++)
      af[i] = *(const bf16x8*)&As[wm + i * 16 + l15][quad * 8];
#pragma unroll
    for (int j = 0; j < 4; j++) {
      bf16x8 bfj = *(const bf16x8*)&Bs[wn + j * 16 + l15][quad * 8];
#pragma unroll
      for (int i = 0; i < 4; i++)
        acc[i][j] = __builtin_amdgcn_mfma_f32_16x16x32_bf16(af[i], bfj, acc[i][j], 0, 0, 0);
    }
  }

#pragma unroll
  for (int i = 0; i < 4; i++) {
    int rb = m0 + wm + i * 16 + quad * 4;
#pragma unroll
    for (int j = 0; j < 4; j++) {
      int col = n0 + wn + j * 16 + l15;
#pragma unroll
      for (int r = 0; r < 4; r++) {
        int row = rb + r;
        if (row >= M) continue;
        epi(row, col, acc[i][j][r]);
      }
    }
  }
}

// f32 output + bias (final projection)
__global__ __launch_bounds__(256) void k_gemm_f32(
    const u16* __restrict__ A, long long a_bs, const u16* __restrict__ Bt,
    const float* __restrict__ bias, float* __restrict__ C, long long c_bs,
    int M, int N, int K)
{
  const u16* Az = A + (size_t)blockIdx.z * a_bs;
  float* Cz = C + (size_t)blockIdx.z * c_bs;
  gemm_core(Az, Bt, M, K, blockIdx.y * 128, blockIdx.x * 128,
            [&](int row, int col, float v) {
              Cz[(size_t)row * N + col] = v + bias[col];
            });
}

// merged q|KV-from-m (y<8) and KV-from-LN(p) (y>=8) GEMMs, one launch
__global__ __launch_bounds__(256) void k_gemm_big(
    const u16* __restrict__ mb, const u16* __restrict__ p,
    const u16* __restrict__ wqkv, const u16* __restrict__ wkv,
    u16* __restrict__ q, u16* __restrict__ KV)
{
  int y = blockIdx.y, z = blockIdx.z;
  if (y < 8) {
    const u16* Az = mb + (size_t)z * (1024 * 512);
    u16* qz  = q  + (size_t)z * (1024 * 512);
    u16* kvz = KV + (size_t)(z * 2267 + 1243) * 1024;
    gemm_core(Az, wqkv, 1024, 512, y * 128, blockIdx.x * 128,
              [&](int row, int col, float v) {
                u16 bv = f2bf(v);
                if (col < 512) qz[(size_t)row * 512 + col] = bv;
                else           kvz[(size_t)row * 1024 + (col - 512)] = bv;
              });
  } else {
    if (blockIdx.x >= 8) return;
    const u16* Az = p + (size_t)z * (1243 * 512);
    u16* kvz = KV + (size_t)z * 2267 * 1024;
    gemm_core(Az, wkv, 1243, 512, (y - 8) * 128, blockIdx.x * 128,
              [&](int row, int col, float v) {
                kvz[(size_t)row * 1024 + col] = f2bf(v);
              });
  }
}

// Segmented conv GEMM (5 residual 1x1 convs) + fused mx transpose-out (s==4)
__global__ __launch_bounds__(256) void k_conv_seg(
    const u16* __restrict__ pool, const u16* __restrict__ wts,
    const float* b0, const float* b1, const float* b2, const float* b3,
    const float* b4, u16* __restrict__ p, float* __restrict__ out2)
{
  int y = blockIdx.y, bz = blockIdx.z;
  int s, m0;
  if (y < 4)      { s = 0; m0 = y * 128; }
  else if (y < 6) { s = 1; m0 = (y - 4) * 128; }
  else if (y < 8) { s = 2; m0 = (y - 6) * 128; }
  else if (y < 9) { s = 3; m0 = 0; }
  else            { s = 4; m0 = (y - 9) * 128; }
  int t0  = s == 0 ? 0 : s == 1 ? 441 : s == 2 ? 697 : s == 3 ? 866 : 987;
  int cnt = s == 0 ? 441 : s == 1 ? 256 : s == 2 ? 169 : s == 3 ? 121 : 256;
  const float* bias = s == 0 ? b0 : s == 1 ? b1 : s == 2 ? b2 : s == 3 ? b3 : b4;
  size_t base = (size_t)bz * (1243 * 512) + (size_t)t0 * 512;
  const u16* Az = pool + base;
  u16* Cz = p + base;
  gemm_core(Az, wts + (size_t)s * 262144, cnt, 512, m0, blockIdx.x * 128,
            [&](int row, int col, float v) {
              v += bias[col] + bf2f(Az[(size_t)row * 512 + col]);
              Cz[(size_t)row * 512 + col] = f2bf(v);
              if (s == 4)                           // mx output [B][C][256] f32
                out2[((size_t)(bz * 512 + col)) * 256 + row] = v;
            });
}

// ---------------------------------------------------------------------------
// LayerNorm in place over C=512
// ---------------------------------------------------------------------------
__global__ __launch_bounds__(256) void k_ln(
    u16* __restrict__ p, const float* __restrict__ g, const float* __restrict__ bb)
{
  __shared__ float red[8];
  size_t row = blockIdx.x;
  u16* pr = p + row * 512;
  int t = threadIdx.x;
  float v0 = bf2f(pr[t]), v1 = bf2f(pr[t + 256]);
  float s = v0 + v1;
#pragma unroll
  for (int off = 1; off < 64; off <<= 1) s += __shfl_xor(s, off);
  int wave = t >> 6;
  if ((t & 63) == 0) red[wave] = s;
  __syncthreads();
  float mean = (red[0] + red[1] + red[2] + red[3]) * (1.f / 512.f);
  float d0 = v0 - mean, d1 = v1 - mean;
  float s2 = d0 * d0 + d1 * d1;
#pragma unroll
  for (int off = 1; off < 64; off <<= 1) s2 += __shfl_xor(s2, off);
  if ((t & 63) == 0) red[4 + wave] = s2;
  __syncthreads();
  float var = (red[4] + red[5] + red[6] + red[7]) * (1.f / 512.f);
  float rstd = rsqrtf(var + 1e-5f);
  pr[t]       = f2bf(d0 * rstd * g[t]       + bb[t]);
  pr[t + 256] = f2bf(d1 * rstd * g[t + 256] + bb[t + 256]);
}

// ---------------------------------------------------------------------------
// MFMA flash attention v5. 64 q/block, 8 waves (qw x kw), 2-phase pipeline.
// LDS-pipe diet vs v4: Q fragments live in registers (loaded from global, no
// Qs buffer); P staged via in-register 4x4 DPP transpose -> cvt_pk_bf16 ->
// one ds_write_b64 per t (replaces 8 conflicted ds_write_b16). Max-free
// softmax (zero-pad tail => subtract 37 from l once). Cross-wave combine is
// a pure sum. LDS = Ks+Vt+Ps = 27648 B.
// ---------------------------------------------------------------------------
__global__ __launch_bounds__(512) void k_attn_mfma(
    const u16* __restrict__ qb, const u16* __restrict__ KV,
    u16* __restrict__ outb)
{
  __shared__ __align__(16) u16 KsV[2][64][72];   // [0]=K [key][dim], [1]=V^T [dim][key]
  __shared__ __align__(16) u16 Psm[64][72];      // P [query][key]
#define Ks_ (KsV[0])
#define Vt_ (KsV[1])

  const int bid = blockIdx.x;
  const int qt = bid >> 6;                  // 0..15, 64 queries each
  const int hb = bid & 63;
  const int h = hb & 7, b = hb >> 3;        // XCD-local KV decode
  const int tid = threadIdx.x;
  const int lane = tid & 63, wv = tid >> 6;
  const int qw = wv >> 1, kw = wv & 1;
  const int quad = lane >> 4, l15 = lane & 15;

  const u16* kvb = KV + (size_t)b * 2267 * 1024;
  const int kr = tid >> 3, kc = (tid & 7) * 8;   // K staging: 1 uint4/thread
  const int vp = tid & 31, vc = (tid >> 5) * 4;  // V staging: key pair x 4 dims

  uint4 kreg = {0, 0, 0, 0};
  uint2 vra = {0, 0}, vrb = {0, 0};
  auto load_tile = [&](int n0) {
    kreg = (uint4){0, 0, 0, 0};
    vra = (uint2){0, 0};
    vrb = (uint2){0, 0};
    if (n0 + kr < 2267)
      kreg = *(const uint4*)(kvb + (size_t)(n0 + kr) * 1024 + h * 64 + kc);
    int na = n0 + 2 * vp;
    const u16* s = kvb + (size_t)na * 1024 + 512 + h * 64 + vc;
    if (na < 2267)     vra = *(const uint2*)s;
    if (na + 1 < 2267) vrb = *(const uint2*)(s + 1024);
  };

  load_tile(0);
  // Q fragments straight from global (rows qt*64+qw*16+l15, dim octets)
  const u16* qrow = qb + (size_t)(b * 1024 + qt * 64 + qw * 16 + l15) * 512 + h * 64;
  bf16x8 aq0 = *(const bf16x8*)(qrow + quad * 8);
  bf16x8 aq1 = *(const bf16x8*)(qrow + 32 + quad * 8);

  float l_acc = 0.f;
  f32x4 o_acc[4];
#pragma unroll
  for (int i = 0; i < 4; i++) o_acc[i] = (f32x4){0.f, 0.f, 0.f, 0.f};

  const bool o1 = (lane & 1) != 0, o2 = (lane & 2) != 0;

  for (int n0 = 0; n0 < 2267; n0 += 64) {
    CFENCE();
    __builtin_amdgcn_s_barrier();                       // prev tile's readers done
    asm volatile("s_waitcnt vmcnt(0)" ::: "memory");    // this tile's regs ready
    *(uint4*)&Ks_[kr][kc] = kreg;
    {
      unsigned lo0 = __builtin_amdgcn_perm(vrb.x, vra.x, 0x05040100u);
      unsigned hi0 = __builtin_amdgcn_perm(vrb.x, vra.x, 0x07060302u);
      unsigned lo1 = __builtin_amdgcn_perm(vrb.y, vra.y, 0x05040100u);
      unsigned hi1 = __builtin_amdgcn_perm(vrb.y, vra.y, 0x07060302u);
      *(unsigned*)&Vt_[vc + 0][2 * vp] = lo0;
      *(unsigned*)&Vt_[vc + 1][2 * vp] = hi0;
      *(unsigned*)&Vt_[vc + 2][2 * vp] = lo1;
      *(unsigned*)&Vt_[vc + 3][2 * vp] = hi1;
    }
    if (n0 + 64 < 2267) load_tile(n0 + 64);             // prefetch next tile
    asm volatile("s_waitcnt lgkmcnt(0)" ::: "memory");  // ds_writes done; vmem in flight
    __builtin_amdgcn_s_barrier();
    CFENCE();

    // ---- S = Q K^T over this wave's 32 keys ----
    f32x4 sacc[2];
#pragma unroll
    for (int t = 0; t < 2; t++) {
      int krow = kw * 32 + t * 16 + l15;
      bf16x8 bk0 = *(const bf16x8*)&Ks_[krow][quad * 8];
      bf16x8 bk1 = *(const bf16x8*)&Ks_[krow][32 + quad * 8];
      f32x4 z = (f32x4){0.f, 0.f, 0.f, 0.f};
      z = __builtin_amdgcn_mfma_f32_16x16x32_bf16(aq0, bk0, z, 0, 0, 0);
      sacc[t] = __builtin_amdgcn_mfma_f32_16x16x32_bf16(aq1, bk1, z, 0, 0, 0);
    }

    // ---- P = exp2(S*scale*log2e); 4x4 DPP transpose -> b64 P-store ----
#pragma unroll
    for (int t = 0; t < 2; t++) {
      float v0 = __builtin_amdgcn_exp2f(fminf(sacc[t][0] * 0.18033688f, 43.28f));
      float v1 = __builtin_amdgcn_exp2f(fminf(sacc[t][1] * 0.18033688f, 43.28f));
      float v2 = __builtin_amdgcn_exp2f(fminf(sacc[t][2] * 0.18033688f, 43.28f));
      float v3 = __builtin_amdgcn_exp2f(fminf(sacc[t][3] * 0.18033688f, 43.28f));
      // transpose 4 lanes x 4 regs (q-index <-> k-index)
      float x, y;
      x = o1 ? v0 : v1; y = qpB1(x); v0 = o1 ? y : v0; v1 = o1 ? v1 : y;
      x = o1 ? v2 : v3; y = qpB1(x); v2 = o1 ? y : v2; v3 = o1 ? v3 : y;
      x = o2 ? v0 : v2; y = qp4E(x); v0 = o2 ? y : v0; v2 = o2 ? v2 : y;
      x = o2 ? v1 : v3; y = qp4E(x); v1 = o2 ? y : v1; v3 = o2 ? v3 : y;
      // lane now holds 4 consecutive-k values for q = qw*16+quad*4+(l15&3)
      l_acc += (v0 + v1) + (v2 + v3);
      uint2 d;
      d.x = cvtpk_bf16(v0, v1);
      d.y = cvtpk_bf16(v2, v3);
      *(uint2*)&Psm[qw * 16 + quad * 4 + (l15 & 3)][kw * 32 + t * 16 + (l15 & 12)] = d;
    }

    // ---- O += P V (wave-local P: DS in-order within wave) ----
    bf16x8 ap = *(const bf16x8*)&Psm[qw * 16 + l15][kw * 32 + quad * 8];
#pragma unroll
    for (int t = 0; t < 4; t++) {
      bf16x8 vf = *(const bf16x8*)&Vt_[t * 16 + l15][kw * 32 + quad * 8];
      o_acc[t] = __builtin_amdgcn_mfma_f32_16x16x32_bf16(ap, vf, o_acc[t], 0, 0, 0);
    }
  }

  // per-lane l covers q = qw*16+quad*4+(l15&3); sum over the g = l15>>2 split
  float l = l_acc;
  l += __shfl_xor(l, 4);
  l += __shfl_xor(l, 8);

  // cross-wave (kw) combine: pure sums (max-free softmax)
  __syncthreads();
  float* Op = (float*)&KsV[0][0][0];   // 64x64 f32 = 16 KB (fits Ks+Vt)
  float* Lp = (float*)&Psm[0][0];      // 64 f32
  if (kw == 1) {
#pragma unroll
    for (int t = 0; t < 4; t++)
#pragma unroll
      for (int r = 0; r < 4; r++)
        Op[(qw * 16 + quad * 4 + r) * 64 + t * 16 + l15] = o_acc[t][r];
    if (l15 < 4) Lp[qw * 16 + quad * 4 + l15] = l;
  }
  __syncthreads();
  if (kw == 0) {
#pragma unroll
    for (int r = 0; r < 4; r++) {
      float lr = __shfl(l, (lane & 60) | r);     // this wave's l for row r
      int row = qw * 16 + quad * 4 + r;
      float lt = lr + Lp[row] - 37.f;            // remove zero-pad tail
      float inv = 1.f / fmaxf(lt, 1e-20f);
#pragma unroll
      for (int t = 0; t < 4; t++) {
        size_t oi = (size_t)(b * 1024 + qt * 64 + row) * 512 + h * 64 + t * 16 + l15;
        outb[oi] = f2bf((o_acc[t][r] + Op[row * 64 + t * 16 + l15]) * inv);
      }
    }
  }
#undef Ks_
#undef Vt_
}

// ---------------------------------------------------------------------------
extern "C" void kernel_launch(void* const* d_in, const int* in_sizes, int n_in,
                              void* d_out, int out_size, void* d_ws, size_t ws_size,
                              hipStream_t stream)
{
  const float* x = (const float*)d_in[0];
  const float* m = (const float*)d_in[1];
  const float* ln_g = (const float*)d_in[12];
  const float* ln_b = (const float*)d_in[13];
  const float* Wq   = (const float*)d_in[14];
  const float* Wkv  = (const float*)d_in[15];
  const float* Wp   = (const float*)d_in[16];
  const float* bp   = (const float*)d_in[17];
  float* out = (float*)d_out;  // out f32 [8,1024,512] | mx f32 [8,512,256]

  // ws (u16 units): pool | p | q | KV | mb | weight-transposes   (~79 MB)
  u16* pool = (u16*)d_ws;
  u16* p    = pool + 5091328;
  u16* q    = p + 5091328;
  u16* KV   = q + 4194304;                 // 8*2267*1024
  u16* mb   = KV + 18571264;               // 8*1024*512
  u16* wt_s = mb + 4194304;                // 5 x 512x512 | wq | wkv | wp
  u16* attn_out = pool;                    // pool dead after conv GEMMs

  // weight prep (one launch)
  k_wt8<<<dim3(32, 16, 8), 256, 0, stream>>>(
      (const float*)d_in[2], (const float*)d_in[4], (const float*)d_in[6],
      (const float*)d_in[8], (const float*)d_in[10], Wq, Wkv, Wp, wt_s);

  // pooling + m conversion, one launch
  k_pool<<<11992, 256, 0, stream>>>(x, pool, m, mb);

  // residual 1x1 convs (MFMA) + fused mx transpose-out, one launch
  k_conv_seg<<<dim3(4, 11, 8), 256, 0, stream>>>(
      pool, wt_s, (const float*)d_in[3], (const float*)d_in[5],
      (const float*)d_in[7], (const float*)d_in[9], (const float*)d_in[11],
      p, out + 4194304);

  k_ln<<<9944, 256, 0, stream>>>(p, ln_g, ln_b);

  // q | KV (both halves), one merged launch
  k_gemm_big<<<dim3(12, 18, 8), 256, 0, stream>>>(
      mb, p, wt_s + 5 * 262144, wt_s + 6 * 262144, q, KV);

  // attention, all batches in one 1D launch (XCD-local KV decode)
  k_attn_mfma<<<1024, 512, 0, stream>>>(q, KV, attn_out);

  // out = attn_out @ Wp + bp -> f32 d_out
  k_gemm_f32<<<dim3(4, 8, 8), 256, 0, stream>>>(attn_out, (long long)1024 * 512,
                                                wt_s + 6 * 262144 + 524288, bp,
                                                out, (long long)1024 * 512,
                                                1024, 512, 512);
  (void)in_sizes; (void)n_in; (void)out_size; (void)ws_size;
}

// Round 4
// 400.575 us; speedup vs baseline: 1.4624x; 1.0218x over previous
//
#include <hip/hip_runtime.h>

typedef unsigned short u16;
typedef __attribute__((ext_vector_type(8))) short bf16x8;
typedef __attribute__((ext_vector_type(4))) float f32x4;
typedef int i32x2 __attribute__((ext_vector_type(2)));

__device__ __forceinline__ float bf2f(u16 u) {
  union { unsigned int i; float f; } x; x.i = ((unsigned int)u) << 16; return x.f;
}
__device__ __forceinline__ u16 f2bf(float f) {
  union { float f; unsigned int i; } x; x.f = f;
  unsigned int r = x.i + 0x7fffu + ((x.i >> 16) & 1u);
  return (u16)(r >> 16);
}

#define CFENCE() asm volatile("" ::: "memory")

__device__ __forceinline__ unsigned cvtpk_bf16(float lo, float hi) {
  unsigned r;
  asm("v_cvt_pk_bf16_f32 %0, %1, %2" : "=v"(r) : "v"(lo), "v"(hi));
  return r;
}

// ---------------------------------------------------------------------------
// Merged pooling + m f32->bf16 convert. Blocks [0,9944): pool; rest: convert.
// ---------------------------------------------------------------------------
__global__ __launch_bounds__(256) void k_pool(
    const float* __restrict__ x, u16* __restrict__ pool,
    const float* __restrict__ m, u16* __restrict__ mb)
{
  int blk = blockIdx.x;
  if (blk >= 9944) {                      // f2b segment (m -> mb)
    size_t i = ((size_t)(blk - 9944) * 256 + threadIdx.x) * 8;
    float4 a = *(const float4*)(m + i);
    float4 b = *(const float4*)(m + i + 4);
    ushort4 u0, u1;
    u0.x = f2bf(a.x); u0.y = f2bf(a.y); u0.z = f2bf(a.z); u0.w = f2bf(a.w);
    u1.x = f2bf(b.x); u1.y = f2bf(b.y); u1.z = f2bf(b.z); u1.w = f2bf(b.w);
    *(ushort4*)(mb + i) = u0;
    *(ushort4*)(mb + i + 4) = u1;
    return;
  }
  int b = blk / 1243;
  int tok = blk - b * 1243;
  int c = threadIdx.x;
  const float* xb = x + (size_t)b * 4096 * 512;
  float r0, r1;
  if (tok >= 987) {                       // maxpool 16x16, 4x4 windows
    int t = tok - 987;
    int oh = t >> 4, ow = t & 15;
    float m0 = -1e38f, m1 = -1e38f;
    for (int hh = 0; hh < 4; hh++)
      for (int ww = 0; ww < 4; ww++) {
        const float* px = xb + (size_t)((oh * 4 + hh) * 64 + ow * 4 + ww) * 512 + c;
        m0 = fmaxf(m0, px[0]);
        m1 = fmaxf(m1, px[256]);
      }
    r0 = m0; r1 = m1;
  } else {                                // adaptive avg, 4 scales
    int n, t;
    if (tok < 441)      { n = 21; t = tok; }
    else if (tok < 697) { n = 16; t = tok - 441; }
    else if (tok < 866) { n = 13; t = tok - 697; }
    else                { n = 11; t = tok - 866; }
    int oh = t / n, ow = t - oh * n;
    int h0 = (oh * 64) / n, h1 = ((oh + 1) * 64 + n - 1) / n;
    int w0 = (ow * 64) / n, w1 = ((ow + 1) * 64 + n - 1) / n;
    float inv = 1.0f / (float)((h1 - h0) * (w1 - w0));
    float s0 = 0.f, s1 = 0.f;
    for (int hh = h0; hh < h1; hh++)
      for (int ww = w0; ww < w1; ww++) {
        const float* px = xb + (size_t)(hh * 64 + ww) * 512 + c;
        s0 += px[0];
        s1 += px[256];
      }
    r0 = s0 * inv; r1 = s1 * inv;
  }
  u16* dst = pool + (size_t)(b * 1243 + tok) * 512 + c;
  dst[0]   = f2bf(r0);
  dst[256] = f2bf(r1);
}

// ---------------------------------------------------------------------------
// Merged weight transpose+convert: all 8 weight matrices in one launch.
// ---------------------------------------------------------------------------
__global__ __launch_bounds__(256) void k_wt8(
    const float* w0, const float* w1, const float* w2, const float* w3,
    const float* w4, const float* w5, const float* w6, const float* w7,
    u16* __restrict__ wt_base)
{
  int z = blockIdx.z;
  int N = (z == 6) ? 1024 : 512;
  if (N == 512 && blockIdx.x >= 16) return;
  const float* W =
      z == 0 ? w0 : z == 1 ? w1 : z == 2 ? w2 : z == 3 ? w3 :
      z == 4 ? w4 : z == 5 ? w5 : z == 6 ? w6 : w7;
  size_t doff = (z <= 5) ? (size_t)z * 262144
                         : (z == 6 ? (size_t)6 * 262144 : (size_t)6 * 262144 + 524288);
  u16* Wt = wt_base + doff;

  __shared__ float tile[32][33];
  int n0 = blockIdx.x * 32, k0 = blockIdx.y * 32;
  int t = threadIdx.x;
  int rr = t >> 5, cc = t & 31;
#pragma unroll
  for (int ps = 0; ps < 4; ps++)
    tile[ps * 8 + rr][cc] = W[(size_t)(k0 + ps * 8 + rr) * N + n0 + cc];
  __syncthreads();
#pragma unroll
  for (int ps = 0; ps < 4; ps++)
    Wt[(size_t)(n0 + ps * 8 + rr) * 512 + k0 + cc] = f2bf(tile[cc][ps * 8 + rr]);
}

// ---------------------------------------------------------------------------
// Pipelined MFMA GEMM core (128x128, BK=32, 4 waves, 2-phase, raw barriers)
// ---------------------------------------------------------------------------
template <class EPI>
__device__ __forceinline__ void gemm_core(
    const u16* __restrict__ Az, const u16* __restrict__ Bt,
    int M, int K, int m0, int n0, EPI&& epi)
{
  __shared__ __align__(16) u16 As[128][40];
  __shared__ __align__(16) u16 Bs[128][40];

  const int tid = threadIdx.x;
  const int lane = tid & 63, wv = tid >> 6;
  const int quad = lane >> 4, l15 = lane & 15;
  const int wm = (wv >> 1) * 64, wn = (wv & 1) * 64;

  f32x4 acc[4][4];
#pragma unroll
  for (int i = 0; i < 4; i++)
#pragma unroll
    for (int j = 0; j < 4; j++) acc[i][j] = (f32x4){0.f, 0.f, 0.f, 0.f};

  const int srow = tid >> 1;
  const int scol = (tid & 1) * 16;
  const bool aok = (m0 + srow) < M;
  const u16* ag = Az + (size_t)(m0 + srow) * K + scol;
  const u16* bg = Bt + (size_t)(n0 + srow) * K + scol;

  uint4 a0 = {0, 0, 0, 0}, a1 = {0, 0, 0, 0}, b0, b1;
  if (aok) { a0 = *(const uint4*)ag; a1 = *(const uint4*)(ag + 8); }
  b0 = *(const uint4*)bg;
  b1 = *(const uint4*)(bg + 8);

  for (int k0 = 0; k0 < K; k0 += 32) {
    CFENCE();
    __builtin_amdgcn_s_barrier();
    asm volatile("s_waitcnt vmcnt(0)" ::: "memory");
    *(uint4*)&As[srow][scol]     = a0;
    *(uint4*)&As[srow][scol + 8] = a1;
    *(uint4*)&Bs[srow][scol]     = b0;
    *(uint4*)&Bs[srow][scol + 8] = b1;
    if (k0 + 32 < K) {
      if (aok) { a0 = *(const uint4*)(ag + k0 + 32); a1 = *(const uint4*)(ag + k0 + 40); }
      b0 = *(const uint4*)(bg + k0 + 32);
      b1 = *(const uint4*)(bg + k0 + 40);
    }
    asm volatile("s_waitcnt lgkmcnt(0)" ::: "memory");
    __builtin_amdgcn_s_barrier();
    CFENCE();

    bf16x8 af[4];
#pragma unroll
    for (int i = 0; i < 4; i++)
      af[i] = *(const bf16x8*)&As[wm + i * 16 + l15][quad * 8];
#pragma unroll
    for (int j = 0; j < 4; j++) {
      bf16x8 bfj = *(const bf16x8*)&Bs[wn + j * 16 + l15][quad * 8];
#pragma unroll
      for (int i = 0; i < 4; i++)
        acc[i][j] = __builtin_amdgcn_mfma_f32_16x16x32_bf16(af[i], bfj, acc[i][j], 0, 0, 0);
    }
  }

#pragma unroll
  for (int i = 0; i < 4; i++) {
    int rb = m0 + wm + i * 16 + quad * 4;
#pragma unroll
    for (int j = 0; j < 4; j++) {
      int col = n0 + wn + j * 16 + l15;
#pragma unroll
      for (int r = 0; r < 4; r++) {
        int row = rb + r;
        if (row >= M) continue;
        epi(row, col, acc[i][j][r]);
      }
    }
  }
}

// f32 output + bias (final projection)
__global__ __launch_bounds__(256) void k_gemm_f32(
    const u16* __restrict__ A, long long a_bs, const u16* __restrict__ Bt,
    const float* __restrict__ bias, float* __restrict__ C, long long c_bs,
    int M, int N, int K)
{
  const u16* Az = A + (size_t)blockIdx.z * a_bs;
  float* Cz = C + (size_t)blockIdx.z * c_bs;
  gemm_core(Az, Bt, M, K, blockIdx.y * 128, blockIdx.x * 128,
            [&](int row, int col, float v) {
              Cz[(size_t)row * N + col] = v + bias[col];
            });
}

// merged q|KV-from-m (y<8) and KV-from-LN(p) (y>=8) GEMMs, one launch
__global__ __launch_bounds__(256) void k_gemm_big(
    const u16* __restrict__ mb, const u16* __restrict__ p,
    const u16* __restrict__ wqkv, const u16* __restrict__ wkv,
    u16* __restrict__ q, u16* __restrict__ KV)
{
  int y = blockIdx.y, z = blockIdx.z;
  if (y < 8) {
    const u16* Az = mb + (size_t)z * (1024 * 512);
    u16* qz  = q  + (size_t)z * (1024 * 512);
    u16* kvz = KV + (size_t)(z * 2267 + 1243) * 1024;
    gemm_core(Az, wqkv, 1024, 512, y * 128, blockIdx.x * 128,
              [&](int row, int col, float v) {
                u16 bv = f2bf(v);
                if (col < 512) qz[(size_t)row * 512 + col] = bv;
                else           kvz[(size_t)row * 1024 + (col - 512)] = bv;
              });
  } else {
    if (blockIdx.x >= 8) return;
    const u16* Az = p + (size_t)z * (1243 * 512);
    u16* kvz = KV + (size_t)z * 2267 * 1024;
    gemm_core(Az, wkv, 1243, 512, (y - 8) * 128, blockIdx.x * 128,
              [&](int row, int col, float v) {
                kvz[(size_t)row * 1024 + col] = f2bf(v);
              });
  }
}

// Segmented conv GEMM (5 residual 1x1 convs) + fused mx transpose-out (s==4)
__global__ __launch_bounds__(256) void k_conv_seg(
    const u16* __restrict__ pool, const u16* __restrict__ wts,
    const float* b0, const float* b1, const float* b2, const float* b3,
    const float* b4, u16* __restrict__ p, float* __restrict__ out2)
{
  int y = blockIdx.y, bz = blockIdx.z;
  int s, m0;
  if (y < 4)      { s = 0; m0 = y * 128; }
  else if (y < 6) { s = 1; m0 = (y - 4) * 128; }
  else if (y < 8) { s = 2; m0 = (y - 6) * 128; }
  else if (y < 9) { s = 3; m0 = 0; }
  else            { s = 4; m0 = (y - 9) * 128; }
  int t0  = s == 0 ? 0 : s == 1 ? 441 : s == 2 ? 697 : s == 3 ? 866 : 987;
  int cnt = s == 0 ? 441 : s == 1 ? 256 : s == 2 ? 169 : s == 3 ? 121 : 256;
  const float* bias = s == 0 ? b0 : s == 1 ? b1 : s == 2 ? b2 : s == 3 ? b3 : b4;
  size_t base = (size_t)bz * (1243 * 512) + (size_t)t0 * 512;
  const u16* Az = pool + base;
  u16* Cz = p + base;
  gemm_core(Az, wts + (size_t)s * 262144, cnt, 512, m0, blockIdx.x * 128,
            [&](int row, int col, float v) {
              v += bias[col] + bf2f(Az[(size_t)row * 512 + col]);
              Cz[(size_t)row * 512 + col] = f2bf(v);
              if (s == 4)                           // mx output [B][C][256] f32
                out2[((size_t)(bz * 512 + col)) * 256 + row] = v;
            });
}

// ---------------------------------------------------------------------------
// LayerNorm in place over C=512
// ---------------------------------------------------------------------------
__global__ __launch_bounds__(256) void k_ln(
    u16* __restrict__ p, const float* __restrict__ g, const float* __restrict__ bb)
{
  __shared__ float red[8];
  size_t row = blockIdx.x;
  u16* pr = p + row * 512;
  int t = threadIdx.x;
  float v0 = bf2f(pr[t]), v1 = bf2f(pr[t + 256]);
  float s = v0 + v1;
#pragma unroll
  for (int off = 1; off < 64; off <<= 1) s += __shfl_xor(s, off);
  int wave = t >> 6;
  if ((t & 63) == 0) red[wave] = s;
  __syncthreads();
  float mean = (red[0] + red[1] + red[2] + red[3]) * (1.f / 512.f);
  float d0 = v0 - mean, d1 = v1 - mean;
  float s2 = d0 * d0 + d1 * d1;
#pragma unroll
  for (int off = 1; off < 64; off <<= 1) s2 += __shfl_xor(s2, off);
  if ((t & 63) == 0) red[4 + wave] = s2;
  __syncthreads();
  float var = (red[4] + red[5] + red[6] + red[7]) * (1.f / 512.f);
  float rstd = rsqrtf(var + 1e-5f);
  pr[t]       = f2bf(d0 * rstd * g[t]       + bb[t]);
  pr[t + 256] = f2bf(d1 * rstd * g[t + 256] + bb[t + 256]);
}

// ---------------------------------------------------------------------------
// MFMA flash attention v6: swapped QK^T (T12). 64 q/block, 8 waves (qw x kw),
// 2-phase pipelined staging. mfma(K,Q) gives S^T: each lane holds 8 scores
// for ONE query (q = l15) -> exp2 -> cvt_pk_bf16 x4 -> permlane32_swap x2
// builds the PV A-fragment fully in registers (NO P LDS round-trip). The
// induced key order is a bit2<->bit3 swap, absorbed by swizzling V's staging
// column (computed once per thread). Softmax denom l is per-lane (per-q):
// 2 shfl_xor at the end. Max-free softmax, zero-pad tail => subtract 37.
// LDS = Ks + Vt = 18432 B.
// ---------------------------------------------------------------------------
__global__ __launch_bounds__(512) void k_attn_mfma(
    const u16* __restrict__ qb, const u16* __restrict__ KV,
    u16* __restrict__ outb)
{
  __shared__ __align__(16) u16 KsV[2][64][72];   // [0]=K [key][dim], [1]=V^T [dim][key-swz]
#define Ks_ (KsV[0])
#define Vt_ (KsV[1])

  const int bid = blockIdx.x;
  const int qt = bid >> 6;                  // 0..15, 64 queries each
  const int hb = bid & 63;
  const int h = hb & 7, b = hb >> 3;        // XCD-local KV decode
  const int tid = threadIdx.x;
  const int lane = tid & 63, wv = tid >> 6;
  const int qw = wv >> 1, kw = wv & 1;
  const int quad = lane >> 4, l15 = lane & 15;

  const u16* kvb = KV + (size_t)b * 2267 * 1024;
  const int kr = tid >> 3, kc = (tid & 7) * 8;   // K staging: 1 uint4/thread
  const int vp = tid & 31, vc = (tid >> 5) * 4;  // V staging: key pair x 4 dims
  // V column swizzle: key offset e -> (e&32) | swap23(e&31); pairs stay adjacent
  const int e2v = 2 * vp;
  const int vcol = (e2v & 32) | (e2v & 0x13) | ((e2v & 4) << 1) | ((e2v & 8) >> 1);

  uint4 kreg = {0, 0, 0, 0};
  uint2 vra = {0, 0}, vrb = {0, 0};
  auto load_tile = [&](int n0) {
    kreg = (uint4){0, 0, 0, 0};
    vra = (uint2){0, 0};
    vrb = (uint2){0, 0};
    if (n0 + kr < 2267)
      kreg = *(const uint4*)(kvb + (size_t)(n0 + kr) * 1024 + h * 64 + kc);
    int na = n0 + 2 * vp;
    const u16* s = kvb + (size_t)na * 1024 + 512 + h * 64 + vc;
    if (na < 2267)     vra = *(const uint2*)s;
    if (na + 1 < 2267) vrb = *(const uint2*)(s + 1024);
  };

  load_tile(0);
  // Q fragments straight from global (q-row = qt*64 + qw*16 + l15)
  const u16* qrow = qb + (size_t)(b * 1024 + qt * 64 + qw * 16 + l15) * 512 + h * 64;
  bf16x8 aq0 = *(const bf16x8*)(qrow + quad * 8);
  bf16x8 aq1 = *(const bf16x8*)(qrow + 32 + quad * 8);

  float l_acc = 0.f;
  f32x4 o_acc[4];
#pragma unroll
  for (int i = 0; i < 4; i++) o_acc[i] = (f32x4){0.f, 0.f, 0.f, 0.f};

  __syncthreads();

  for (int n0 = 0; n0 < 2267; n0 += 64) {
    CFENCE();
    __builtin_amdgcn_s_barrier();                       // prev tile's readers done
    asm volatile("s_waitcnt vmcnt(0)" ::: "memory");    // this tile's regs ready
    *(uint4*)&Ks_[kr][kc] = kreg;
    {
      unsigned lo0 = __builtin_amdgcn_perm(vrb.x, vra.x, 0x05040100u);
      unsigned hi0 = __builtin_amdgcn_perm(vrb.x, vra.x, 0x07060302u);
      unsigned lo1 = __builtin_amdgcn_perm(vrb.y, vra.y, 0x05040100u);
      unsigned hi1 = __builtin_amdgcn_perm(vrb.y, vra.y, 0x07060302u);
      *(unsigned*)&Vt_[vc + 0][vcol] = lo0;
      *(unsigned*)&Vt_[vc + 1][vcol] = hi0;
      *(unsigned*)&Vt_[vc + 2][vcol] = lo1;
      *(unsigned*)&Vt_[vc + 3][vcol] = hi1;
    }
    if (n0 + 64 < 2267) load_tile(n0 + 64);             // prefetch next tile
    asm volatile("s_waitcnt lgkmcnt(0)" ::: "memory");  // ds_writes done; vmem in flight
    __builtin_amdgcn_s_barrier();
    CFENCE();

    // ---- S^T = K Q^T over this wave's 32 keys (swapped operands) ----
    f32x4 sacc[2];
#pragma unroll
    for (int t = 0; t < 2; t++) {
      int krow = kw * 32 + t * 16 + l15;
      bf16x8 bk0 = *(const bf16x8*)&Ks_[krow][quad * 8];
      bf16x8 bk1 = *(const bf16x8*)&Ks_[krow][32 + quad * 8];
      f32x4 z = (f32x4){0.f, 0.f, 0.f, 0.f};
      z = __builtin_amdgcn_mfma_f32_16x16x32_bf16(bk0, aq0, z, 0, 0, 0);
      sacc[t] = __builtin_amdgcn_mfma_f32_16x16x32_bf16(bk1, aq1, z, 0, 0, 0);
    }

    // ---- P = exp2(S*scale*log2e); pack + permlane32_swap -> PV A-frag ----
    unsigned Pk[4];
#pragma unroll
    for (int t = 0; t < 2; t++) {
      float e0 = __builtin_amdgcn_exp2f(fminf(sacc[t][0] * 0.18033688f, 43.28f));
      float e1 = __builtin_amdgcn_exp2f(fminf(sacc[t][1] * 0.18033688f, 43.28f));
      float e2 = __builtin_amdgcn_exp2f(fminf(sacc[t][2] * 0.18033688f, 43.28f));
      float e3 = __builtin_amdgcn_exp2f(fminf(sacc[t][3] * 0.18033688f, 43.28f));
      l_acc += (e0 + e1) + (e2 + e3);
      Pk[2 * t]     = cvtpk_bf16(e0, e1);
      Pk[2 * t + 1] = cvtpk_bf16(e2, e3);
    }
    // rows: new_a=[a0,a1,b0,b1], new_b=[a2,a3,b2,b3] (16-lane row units)
    i32x2 sA = __builtin_amdgcn_permlane32_swap((int)Pk[0], (int)Pk[2], false, false);
    i32x2 sB = __builtin_amdgcn_permlane32_swap((int)Pk[1], (int)Pk[3], false, false);
    uint4 au;
    au.x = (unsigned)sA[0]; au.y = (unsigned)sB[0];
    au.z = (unsigned)sA[1]; au.w = (unsigned)sB[1];
    bf16x8 ap = __builtin_bit_cast(bf16x8, au);

    // ---- O += P V (V staged with matching column swizzle) ----
#pragma unroll
    for (int t = 0; t < 4; t++) {
      bf16x8 vf = *(const bf16x8*)&Vt_[t * 16 + l15][kw * 32 + quad * 8];
      o_acc[t] = __builtin_amdgcn_mfma_f32_16x16x32_bf16(ap, vf, o_acc[t], 0, 0, 0);
    }
  }

  // l is per-lane (q = qw*16 + l15), partial over this wave's keys x quad rows
  l_acc += __shfl_xor(l_acc, 16);
  l_acc += __shfl_xor(l_acc, 32);

  // cross-wave (kw) combine: pure sums (max-free softmax)
  __syncthreads();
  float* Op = (float*)&KsV[0][0][0];   // 64x64 f32 = 16 KB
  float* Lp = Op + 4096;               // 64 f32 (fits: LDS total 18432 B)
  if (kw == 1) {
#pragma unroll
    for (int t = 0; t < 4; t++)
#pragma unroll
      for (int r = 0; r < 4; r++)
        Op[(qw * 16 + quad * 4 + r) * 64 + t * 16 + l15] = o_acc[t][r];
    if (quad == 0) Lp[qw * 16 + l15] = l_acc;
  }
  __syncthreads();
  if (kw == 0) {
#pragma unroll
    for (int r = 0; r < 4; r++) {
      int row = qw * 16 + quad * 4 + r;
      float lq = __shfl(l_acc, (lane & 48) | (quad * 4 + r));  // own-wave l(q=row)
      float lt = lq + Lp[row] - 37.f;            // remove zero-pad tail
      float inv = 1.f / fmaxf(lt, 1e-20f);
#pragma unroll
      for (int t = 0; t < 4; t++) {
        size_t oi = (size_t)(b * 1024 + qt * 64 + row) * 512 + h * 64 + t * 16 + l15;
        outb[oi] = f2bf((o_acc[t][r] + Op[row * 64 + t * 16 + l15]) * inv);
      }
    }
  }
#undef Ks_
#undef Vt_
}

// ---------------------------------------------------------------------------
extern "C" void kernel_launch(void* const* d_in, const int* in_sizes, int n_in,
                              void* d_out, int out_size, void* d_ws, size_t ws_size,
                              hipStream_t stream)
{
  const float* x = (const float*)d_in[0];
  const float* m = (const float*)d_in[1];
  const float* ln_g = (const float*)d_in[12];
  const float* ln_b = (const float*)d_in[13];
  const float* Wq   = (const float*)d_in[14];
  const float* Wkv  = (const float*)d_in[15];
  const float* Wp   = (const float*)d_in[16];
  const float* bp   = (const float*)d_in[17];
  float* out = (float*)d_out;  // out f32 [8,1024,512] | mx f32 [8,512,256]

  // ws (u16 units): pool | p | q | KV | mb | weight-transposes   (~79 MB)
  u16* pool = (u16*)d_ws;
  u16* p    = pool + 5091328;
  u16* q    = p + 5091328;
  u16* KV   = q + 4194304;                 // 8*2267*1024
  u16* mb   = KV + 18571264;               // 8*1024*512
  u16* wt_s = mb + 4194304;                // 5 x 512x512 | wq | wkv | wp
  u16* attn_out = pool;                    // pool dead after conv GEMMs

  // weight prep (one launch)
  k_wt8<<<dim3(32, 16, 8), 256, 0, stream>>>(
      (const float*)d_in[2], (const float*)d_in[4], (const float*)d_in[6],
      (const float*)d_in[8], (const float*)d_in[10], Wq, Wkv, Wp, wt_s);

  // pooling + m conversion, one launch
  k_pool<<<11992, 256, 0, stream>>>(x, pool, m, mb);

  // residual 1x1 convs (MFMA) + fused mx transpose-out, one launch
  k_conv_seg<<<dim3(4, 11, 8), 256, 0, stream>>>(
      pool, wt_s, (const float*)d_in[3], (const float*)d_in[5],
      (const float*)d_in[7], (const float*)d_in[9], (const float*)d_in[11],
      p, out + 4194304);

  k_ln<<<9944, 256, 0, stream>>>(p, ln_g, ln_b);

  // q | KV (both halves), one merged launch
  k_gemm_big<<<dim3(12, 18, 8), 256, 0, stream>>>(
      mb, p, wt_s + 5 * 262144, wt_s + 6 * 262144, q, KV);

  // attention, all batches in one 1D launch (XCD-local KV decode)
  k_attn_mfma<<<1024, 512, 0, stream>>>(q, KV, attn_out);

  // out = attn_out @ Wp + bp -> f32 d_out
  k_gemm_f32<<<dim3(4, 8, 8), 256, 0, stream>>>(attn_out, (long long)1024 * 512,
                                                wt_s + 6 * 262144 + 524288, bp,
                                                out, (long long)1024 * 512,
                                                1024, 512, 512);
  (void)in_sizes; (void)n_in; (void)out_size; (void)ws_size;
}

// Round 5
// 366.342 us; speedup vs baseline: 1.5990x; 1.0934x over previous
//
#include <hip/hip_runtime.h>

typedef unsigned short u16;
typedef __attribute__((ext_vector_type(8))) short bf16x8;
typedef __attribute__((ext_vector_type(4))) float f32x4;
typedef int i32x2 __attribute__((ext_vector_type(2)));

__device__ __forceinline__ float bf2f(u16 u) {
  union { unsigned int i; float f; } x; x.i = ((unsigned int)u) << 16; return x.f;
}
__device__ __forceinline__ u16 f2bf(float f) {
  union { float f; unsigned int i; } x; x.f = f;
  unsigned int r = x.i + 0x7fffu + ((x.i >> 16) & 1u);
  return (u16)(r >> 16);
}

#define CFENCE() asm volatile("" ::: "memory")

__device__ __forceinline__ unsigned cvtpk_bf16(float lo, float hi) {
  unsigned r;
  asm("v_cvt_pk_bf16_f32 %0, %1, %2" : "=v"(r) : "v"(lo), "v"(hi));
  return r;
}

// ---------------------------------------------------------------------------
// Merged pooling + m f32->bf16 convert. Blocks [0,9944): pool; rest: convert.
// ---------------------------------------------------------------------------
__global__ __launch_bounds__(256) void k_pool(
    const float* __restrict__ x, u16* __restrict__ pool,
    const float* __restrict__ m, u16* __restrict__ mb)
{
  int blk = blockIdx.x;
  if (blk >= 9944) {                      // f2b segment (m -> mb)
    size_t i = ((size_t)(blk - 9944) * 256 + threadIdx.x) * 8;
    float4 a = *(const float4*)(m + i);
    float4 b = *(const float4*)(m + i + 4);
    ushort4 u0, u1;
    u0.x = f2bf(a.x); u0.y = f2bf(a.y); u0.z = f2bf(a.z); u0.w = f2bf(a.w);
    u1.x = f2bf(b.x); u1.y = f2bf(b.y); u1.z = f2bf(b.z); u1.w = f2bf(b.w);
    *(ushort4*)(mb + i) = u0;
    *(ushort4*)(mb + i + 4) = u1;
    return;
  }
  int b = blk / 1243;
  int tok = blk - b * 1243;
  int c = threadIdx.x;
  const float* xb = x + (size_t)b * 4096 * 512;
  float r0, r1;
  if (tok >= 987) {                       // maxpool 16x16, 4x4 windows
    int t = tok - 987;
    int oh = t >> 4, ow = t & 15;
    float m0 = -1e38f, m1 = -1e38f;
    for (int hh = 0; hh < 4; hh++)
      for (int ww = 0; ww < 4; ww++) {
        const float* px = xb + (size_t)((oh * 4 + hh) * 64 + ow * 4 + ww) * 512 + c;
        m0 = fmaxf(m0, px[0]);
        m1 = fmaxf(m1, px[256]);
      }
    r0 = m0; r1 = m1;
  } else {                                // adaptive avg, 4 scales
    int n, t;
    if (tok < 441)      { n = 21; t = tok; }
    else if (tok < 697) { n = 16; t = tok - 441; }
    else if (tok < 866) { n = 13; t = tok - 697; }
    else                { n = 11; t = tok - 866; }
    int oh = t / n, ow = t - oh * n;
    int h0 = (oh * 64) / n, h1 = ((oh + 1) * 64 + n - 1) / n;
    int w0 = (ow * 64) / n, w1 = ((ow + 1) * 64 + n - 1) / n;
    float inv = 1.0f / (float)((h1 - h0) * (w1 - w0));
    float s0 = 0.f, s1 = 0.f;
    for (int hh = h0; hh < h1; hh++)
      for (int ww = w0; ww < w1; ww++) {
        const float* px = xb + (size_t)(hh * 64 + ww) * 512 + c;
        s0 += px[0];
        s1 += px[256];
      }
    r0 = s0 * inv; r1 = s1 * inv;
  }
  u16* dst = pool + (size_t)(b * 1243 + tok) * 512 + c;
  dst[0]   = f2bf(r0);
  dst[256] = f2bf(r1);
}

// ---------------------------------------------------------------------------
// Merged weight transpose+convert: all 8 weight matrices in one launch.
// ---------------------------------------------------------------------------
__global__ __launch_bounds__(256) void k_wt8(
    const float* w0, const float* w1, const float* w2, const float* w3,
    const float* w4, const float* w5, const float* w6, const float* w7,
    u16* __restrict__ wt_base)
{
  int z = blockIdx.z;
  int N = (z == 6) ? 1024 : 512;
  if (N == 512 && blockIdx.x >= 16) return;
  const float* W =
      z == 0 ? w0 : z == 1 ? w1 : z == 2 ? w2 : z == 3 ? w3 :
      z == 4 ? w4 : z == 5 ? w5 : z == 6 ? w6 : w7;
  size_t doff = (z <= 5) ? (size_t)z * 262144
                         : (z == 6 ? (size_t)6 * 262144 : (size_t)6 * 262144 + 524288);
  u16* Wt = wt_base + doff;

  __shared__ float tile[32][33];
  int n0 = blockIdx.x * 32, k0 = blockIdx.y * 32;
  int t = threadIdx.x;
  int rr = t >> 5, cc = t & 31;
#pragma unroll
  for (int ps = 0; ps < 4; ps++)
    tile[ps * 8 + rr][cc] = W[(size_t)(k0 + ps * 8 + rr) * N + n0 + cc];
  __syncthreads();
#pragma unroll
  for (int ps = 0; ps < 4; ps++)
    Wt[(size_t)(n0 + ps * 8 + rr) * 512 + k0 + cc] = f2bf(tile[cc][ps * 8 + rr]);
}

// ---------------------------------------------------------------------------
// Pipelined MFMA GEMM core (128x128, BK=32, 4 waves, 2-phase, raw barriers)
// ---------------------------------------------------------------------------
template <class EPI>
__device__ __forceinline__ void gemm_core(
    const u16* __restrict__ Az, const u16* __restrict__ Bt,
    int M, int K, int m0, int n0, EPI&& epi)
{
  __shared__ __align__(16) u16 As[128][40];
  __shared__ __align__(16) u16 Bs[128][40];

  const int tid = threadIdx.x;
  const int lane = tid & 63, wv = tid >> 6;
  const int quad = lane >> 4, l15 = lane & 15;
  const int wm = (wv >> 1) * 64, wn = (wv & 1) * 64;

  f32x4 acc[4][4];
#pragma unroll
  for (int i = 0; i < 4; i++)
#pragma unroll
    for (int j = 0; j < 4; j++) acc[i][j] = (f32x4){0.f, 0.f, 0.f, 0.f};

  const int srow = tid >> 1;
  const int scol = (tid & 1) * 16;
  const bool aok = (m0 + srow) < M;
  const u16* ag = Az + (size_t)(m0 + srow) * K + scol;
  const u16* bg = Bt + (size_t)(n0 + srow) * K + scol;

  uint4 a0 = {0, 0, 0, 0}, a1 = {0, 0, 0, 0}, b0, b1;
  if (aok) { a0 = *(const uint4*)ag; a1 = *(const uint4*)(ag + 8); }
  b0 = *(const uint4*)bg;
  b1 = *(const uint4*)(bg + 8);

  for (int k0 = 0; k0 < K; k0 += 32) {
    CFENCE();
    __builtin_amdgcn_s_barrier();
    asm volatile("s_waitcnt vmcnt(0)" ::: "memory");
    *(uint4*)&As[srow][scol]     = a0;
    *(uint4*)&As[srow][scol + 8] = a1;
    *(uint4*)&Bs[srow][scol]     = b0;
    *(uint4*)&Bs[srow][scol + 8] = b1;
    if (k0 + 32 < K) {
      if (aok) { a0 = *(const uint4*)(ag + k0 + 32); a1 = *(const uint4*)(ag + k0 + 40); }
      b0 = *(const uint4*)(bg + k0 + 32);
      b1 = *(const uint4*)(bg + k0 + 40);
    }
    asm volatile("s_waitcnt lgkmcnt(0)" ::: "memory");
    __builtin_amdgcn_s_barrier();
    CFENCE();

    bf16x8 af[4];
#pragma unroll
    for (int i = 0; i < 4; i++)
      af[i] = *(const bf16x8*)&As[wm + i * 16 + l15][quad * 8];
#pragma unroll
    for (int j = 0; j < 4; j++) {
      bf16x8 bfj = *(const bf16x8*)&Bs[wn + j * 16 + l15][quad * 8];
#pragma unroll
      for (int i = 0; i < 4; i++)
        acc[i][j] = __builtin_amdgcn_mfma_f32_16x16x32_bf16(af[i], bfj, acc[i][j], 0, 0, 0);
    }
  }

#pragma unroll
  for (int i = 0; i < 4; i++) {
    int rb = m0 + wm + i * 16 + quad * 4;
#pragma unroll
    for (int j = 0; j < 4; j++) {
      int col = n0 + wn + j * 16 + l15;
#pragma unroll
      for (int r = 0; r < 4; r++) {
        int row = rb + r;
        if (row >= M) continue;
        epi(row, col, acc[i][j][r]);
      }
    }
  }
}

// f32 output + bias (final projection)
__global__ __launch_bounds__(256) void k_gemm_f32(
    const u16* __restrict__ A, long long a_bs, const u16* __restrict__ Bt,
    const float* __restrict__ bias, float* __restrict__ C, long long c_bs,
    int M, int N, int K)
{
  const u16* Az = A + (size_t)blockIdx.z * a_bs;
  float* Cz = C + (size_t)blockIdx.z * c_bs;
  gemm_core(Az, Bt, M, K, blockIdx.y * 128, blockIdx.x * 128,
            [&](int row, int col, float v) {
              Cz[(size_t)row * N + col] = v + bias[col];
            });
}

// merged q|KV-from-m (y<8) and KV-from-LN(p) (y>=8) GEMMs, one launch
__global__ __launch_bounds__(256) void k_gemm_big(
    const u16* __restrict__ mb, const u16* __restrict__ p,
    const u16* __restrict__ wqkv, const u16* __restrict__ wkv,
    u16* __restrict__ q, u16* __restrict__ KV)
{
  int y = blockIdx.y, z = blockIdx.z;
  if (y < 8) {
    const u16* Az = mb + (size_t)z * (1024 * 512);
    u16* qz  = q  + (size_t)z * (1024 * 512);
    u16* kvz = KV + (size_t)(z * 2267 + 1243) * 1024;
    gemm_core(Az, wqkv, 1024, 512, y * 128, blockIdx.x * 128,
              [&](int row, int col, float v) {
                u16 bv = f2bf(v);
                if (col < 512) qz[(size_t)row * 512 + col] = bv;
                else           kvz[(size_t)row * 1024 + (col - 512)] = bv;
              });
  } else {
    if (blockIdx.x >= 8) return;
    const u16* Az = p + (size_t)z * (1243 * 512);
    u16* kvz = KV + (size_t)z * 2267 * 1024;
    gemm_core(Az, wkv, 1243, 512, (y - 8) * 128, blockIdx.x * 128,
              [&](int row, int col, float v) {
                kvz[(size_t)row * 1024 + col] = f2bf(v);
              });
  }
}

// Segmented conv GEMM (5 residual 1x1 convs) + fused mx transpose-out (s==4)
__global__ __launch_bounds__(256) void k_conv_seg(
    const u16* __restrict__ pool, const u16* __restrict__ wts,
    const float* b0, const float* b1, const float* b2, const float* b3,
    const float* b4, u16* __restrict__ p, float* __restrict__ out2)
{
  int y = blockIdx.y, bz = blockIdx.z;
  int s, m0;
  if (y < 4)      { s = 0; m0 = y * 128; }
  else if (y < 6) { s = 1; m0 = (y - 4) * 128; }
  else if (y < 8) { s = 2; m0 = (y - 6) * 128; }
  else if (y < 9) { s = 3; m0 = 0; }
  else            { s = 4; m0 = (y - 9) * 128; }
  int t0  = s == 0 ? 0 : s == 1 ? 441 : s == 2 ? 697 : s == 3 ? 866 : 987;
  int cnt = s == 0 ? 441 : s == 1 ? 256 : s == 2 ? 169 : s == 3 ? 121 : 256;
  const float* bias = s == 0 ? b0 : s == 1 ? b1 : s == 2 ? b2 : s == 3 ? b3 : b4;
  size_t base = (size_t)bz * (1243 * 512) + (size_t)t0 * 512;
  const u16* Az = pool + base;
  u16* Cz = p + base;
  gemm_core(Az, wts + (size_t)s * 262144, cnt, 512, m0, blockIdx.x * 128,
            [&](int row, int col, float v) {
              v += bias[col] + bf2f(Az[(size_t)row * 512 + col]);
              Cz[(size_t)row * 512 + col] = f2bf(v);
              if (s == 4)                           // mx output [B][C][256] f32
                out2[((size_t)(bz * 512 + col)) * 256 + row] = v;
            });
}

// ---------------------------------------------------------------------------
// LayerNorm in place over C=512
// ---------------------------------------------------------------------------
__global__ __launch_bounds__(256) void k_ln(
    u16* __restrict__ p, const float* __restrict__ g, const float* __restrict__ bb)
{
  __shared__ float red[8];
  size_t row = blockIdx.x;
  u16* pr = p + row * 512;
  int t = threadIdx.x;
  float v0 = bf2f(pr[t]), v1 = bf2f(pr[t + 256]);
  float s = v0 + v1;
#pragma unroll
  for (int off = 1; off < 64; off <<= 1) s += __shfl_xor(s, off);
  int wave = t >> 6;
  if ((t & 63) == 0) red[wave] = s;
  __syncthreads();
  float mean = (red[0] + red[1] + red[2] + red[3]) * (1.f / 512.f);
  float d0 = v0 - mean, d1 = v1 - mean;
  float s2 = d0 * d0 + d1 * d1;
#pragma unroll
  for (int off = 1; off < 64; off <<= 1) s2 += __shfl_xor(s2, off);
  if ((t & 63) == 0) red[4 + wave] = s2;
  __syncthreads();
  float var = (red[4] + red[5] + red[6] + red[7]) * (1.f / 512.f);
  float rstd = rsqrtf(var + 1e-5f);
  pr[t]       = f2bf(d0 * rstd * g[t]       + bb[t]);
  pr[t + 256] = f2bf(d1 * rstd * g[t + 256] + bb[t + 256]);
}

// ---------------------------------------------------------------------------
// MFMA flash attention v7: 128 queries/block, 8 waves, NO key-split.
// Each wave owns 16 queries x all 64 staged keys (two 32-key slabs s=0,1
// reusing the block's staged K/V). Vs v6 this halves global staging+barrier
// cost per key (8 blocks per (h,b) instead of 16) and deletes the cross-wave
// combine (each wave's l and O are complete; no epilogue syncthreads).
// Swapped QK^T (T12): lane holds scores for ONE query (q=l15); exp2 ->
// cvt_pk_bf16 -> permlane32_swap builds PV A-frags in registers; V staging
// column swizzle absorbs the induced key order. Max-free softmax with
// zero-pad tail (subtract 37 from l). 2-phase pipelined staging, s_setprio
// around compute slabs (T5). Grid 512 = 8 qt x 64 (h,b): XCD-local KV.
// LDS = Ks + Vt = 18432 B.
// ---------------------------------------------------------------------------
__global__ __launch_bounds__(512) void k_attn_mfma(
    const u16* __restrict__ qb, const u16* __restrict__ KV,
    u16* __restrict__ outb)
{
  __shared__ __align__(16) u16 KsV[2][64][72];   // [0]=K [key][dim], [1]=V^T [dim][key-swz]
#define Ks_ (KsV[0])
#define Vt_ (KsV[1])

  const int bid = blockIdx.x;
  const int qt = bid >> 6;                  // 0..7, 128 queries each
  const int hb = bid & 63;
  const int h = hb & 7, b = hb >> 3;        // XCD-local KV decode
  const int tid = threadIdx.x;
  const int lane = tid & 63, wv = tid >> 6; // wave owns queries wv*16..+16
  const int quad = lane >> 4, l15 = lane & 15;

  const u16* kvb = KV + (size_t)b * 2267 * 1024;
  const int kr = tid >> 3, kc = (tid & 7) * 8;   // K staging: 1 uint4/thread
  const int vp = tid & 31, vc = (tid >> 5) * 4;  // V staging: key pair x 4 dims
  // V column swizzle: key offset e -> (e&32) | swap23(e&31); pairs stay adjacent
  const int e2v = 2 * vp;
  const int vcol = (e2v & 32) | (e2v & 0x13) | ((e2v & 4) << 1) | ((e2v & 8) >> 1);

  uint4 kreg = {0, 0, 0, 0};
  uint2 vra = {0, 0}, vrb = {0, 0};
  auto load_tile = [&](int n0) {
    kreg = (uint4){0, 0, 0, 0};
    vra = (uint2){0, 0};
    vrb = (uint2){0, 0};
    if (n0 + kr < 2267)
      kreg = *(const uint4*)(kvb + (size_t)(n0 + kr) * 1024 + h * 64 + kc);
    int na = n0 + 2 * vp;
    const u16* s = kvb + (size_t)na * 1024 + 512 + h * 64 + vc;
    if (na < 2267)     vra = *(const uint2*)s;
    if (na + 1 < 2267) vrb = *(const uint2*)(s + 1024);
  };

  load_tile(0);
  // Q fragments straight from global (q-row = qt*128 + wv*16 + l15)
  const u16* qrow = qb + (size_t)(b * 1024 + qt * 128 + wv * 16 + l15) * 512 + h * 64;
  bf16x8 aq0 = *(const bf16x8*)(qrow + quad * 8);
  bf16x8 aq1 = *(const bf16x8*)(qrow + 32 + quad * 8);

  float l_acc = 0.f;
  f32x4 o_acc[4];
#pragma unroll
  for (int i = 0; i < 4; i++) o_acc[i] = (f32x4){0.f, 0.f, 0.f, 0.f};

  __syncthreads();

  for (int n0 = 0; n0 < 2267; n0 += 64) {
    CFENCE();
    __builtin_amdgcn_s_barrier();                       // prev tile's readers done
    asm volatile("s_waitcnt vmcnt(0)" ::: "memory");    // this tile's regs ready
    *(uint4*)&Ks_[kr][kc] = kreg;
    {
      unsigned lo0 = __builtin_amdgcn_perm(vrb.x, vra.x, 0x05040100u);
      unsigned hi0 = __builtin_amdgcn_perm(vrb.x, vra.x, 0x07060302u);
      unsigned lo1 = __builtin_amdgcn_perm(vrb.y, vra.y, 0x05040100u);
      unsigned hi1 = __builtin_amdgcn_perm(vrb.y, vra.y, 0x07060302u);
      *(unsigned*)&Vt_[vc + 0][vcol] = lo0;
      *(unsigned*)&Vt_[vc + 1][vcol] = hi0;
      *(unsigned*)&Vt_[vc + 2][vcol] = lo1;
      *(unsigned*)&Vt_[vc + 3][vcol] = hi1;
    }
    if (n0 + 64 < 2267) load_tile(n0 + 64);             // prefetch next tile
    asm volatile("s_waitcnt lgkmcnt(0)" ::: "memory");  // ds_writes done; vmem in flight
    __builtin_amdgcn_s_barrier();
    CFENCE();

    // ---- two 32-key slabs: S^T = K Q^T -> exp2 -> in-reg P -> O += P V ----
#pragma unroll
    for (int s = 0; s < 2; s++) {
      f32x4 sacc[2];
      __builtin_amdgcn_s_setprio(1);
#pragma unroll
      for (int t = 0; t < 2; t++) {
        int krow = s * 32 + t * 16 + l15;
        bf16x8 bk0 = *(const bf16x8*)&Ks_[krow][quad * 8];
        bf16x8 bk1 = *(const bf16x8*)&Ks_[krow][32 + quad * 8];
        f32x4 z = (f32x4){0.f, 0.f, 0.f, 0.f};
        z = __builtin_amdgcn_mfma_f32_16x16x32_bf16(bk0, aq0, z, 0, 0, 0);
        sacc[t] = __builtin_amdgcn_mfma_f32_16x16x32_bf16(bk1, aq1, z, 0, 0, 0);
      }
      __builtin_amdgcn_s_setprio(0);

      unsigned Pk[4];
#pragma unroll
      for (int t = 0; t < 2; t++) {
        float e0 = __builtin_amdgcn_exp2f(fminf(sacc[t][0] * 0.18033688f, 43.28f));
        float e1 = __builtin_amdgcn_exp2f(fminf(sacc[t][1] * 0.18033688f, 43.28f));
        float e2 = __builtin_amdgcn_exp2f(fminf(sacc[t][2] * 0.18033688f, 43.28f));
        float e3 = __builtin_amdgcn_exp2f(fminf(sacc[t][3] * 0.18033688f, 43.28f));
        l_acc += (e0 + e1) + (e2 + e3);
        Pk[2 * t]     = cvtpk_bf16(e0, e1);
        Pk[2 * t + 1] = cvtpk_bf16(e2, e3);
      }
      i32x2 sA = __builtin_amdgcn_permlane32_swap((int)Pk[0], (int)Pk[2], false, false);
      i32x2 sB = __builtin_amdgcn_permlane32_swap((int)Pk[1], (int)Pk[3], false, false);
      uint4 au;
      au.x = (unsigned)sA[0]; au.y = (unsigned)sB[0];
      au.z = (unsigned)sA[1]; au.w = (unsigned)sB[1];
      bf16x8 ap = __builtin_bit_cast(bf16x8, au);

      __builtin_amdgcn_s_setprio(1);
#pragma unroll
      for (int t = 0; t < 4; t++) {
        bf16x8 vf = *(const bf16x8*)&Vt_[t * 16 + l15][s * 32 + quad * 8];
        o_acc[t] = __builtin_amdgcn_mfma_f32_16x16x32_bf16(ap, vf, o_acc[t], 0, 0, 0);
      }
      __builtin_amdgcn_s_setprio(0);
    }
  }

  // l: sum over quad groups (keys were split across quads); per-lane q = l15
  l_acc += __shfl_xor(l_acc, 16);
  l_acc += __shfl_xor(l_acc, 32);

  // epilogue: fully wave-local (no cross-wave combine)
#pragma unroll
  for (int r = 0; r < 4; r++) {
    int row = wv * 16 + quad * 4 + r;
    float lq = __shfl(l_acc, (lane & 48) | (quad * 4 + r));  // l for q = quad*4+r
    float lt = lq - 37.f;                    // remove zero-pad tail contribution
    float inv = 1.f / fmaxf(lt, 1e-20f);
#pragma unroll
    for (int t = 0; t < 4; t++) {
      size_t oi = (size_t)(b * 1024 + qt * 128 + row) * 512 + h * 64 + t * 16 + l15;
      outb[oi] = f2bf(o_acc[t][r] * inv);
    }
  }
#undef Ks_
#undef Vt_
}

// ---------------------------------------------------------------------------
extern "C" void kernel_launch(void* const* d_in, const int* in_sizes, int n_in,
                              void* d_out, int out_size, void* d_ws, size_t ws_size,
                              hipStream_t stream)
{
  const float* x = (const float*)d_in[0];
  const float* m = (const float*)d_in[1];
  const float* ln_g = (const float*)d_in[12];
  const float* ln_b = (const float*)d_in[13];
  const float* Wq   = (const float*)d_in[14];
  const float* Wkv  = (const float*)d_in[15];
  const float* Wp   = (const float*)d_in[16];
  const float* bp   = (const float*)d_in[17];
  float* out = (float*)d_out;  // out f32 [8,1024,512] | mx f32 [8,512,256]

  // ws (u16 units): pool | p | q | KV | mb | weight-transposes   (~79 MB)
  u16* pool = (u16*)d_ws;
  u16* p    = pool + 5091328;
  u16* q    = p + 5091328;
  u16* KV   = q + 4194304;                 // 8*2267*1024
  u16* mb   = KV + 18571264;               // 8*1024*512
  u16* wt_s = mb + 4194304;                // 5 x 512x512 | wq | wkv | wp
  u16* attn_out = pool;                    // pool dead after conv GEMMs

  // weight prep (one launch)
  k_wt8<<<dim3(32, 16, 8), 256, 0, stream>>>(
      (const float*)d_in[2], (const float*)d_in[4], (const float*)d_in[6],
      (const float*)d_in[8], (const float*)d_in[10], Wq, Wkv, Wp, wt_s);

  // pooling + m conversion, one launch
  k_pool<<<11992, 256, 0, stream>>>(x, pool, m, mb);

  // residual 1x1 convs (MFMA) + fused mx transpose-out, one launch
  k_conv_seg<<<dim3(4, 11, 8), 256, 0, stream>>>(
      pool, wt_s, (const float*)d_in[3], (const float*)d_in[5],
      (const float*)d_in[7], (const float*)d_in[9], (const float*)d_in[11],
      p, out + 4194304);

  k_ln<<<9944, 256, 0, stream>>>(p, ln_g, ln_b);

  // q | KV (both halves), one merged launch
  k_gemm_big<<<dim3(12, 18, 8), 256, 0, stream>>>(
      mb, p, wt_s + 5 * 262144, wt_s + 6 * 262144, q, KV);

  // attention: 512 blocks (128 q each), XCD-local KV decode
  k_attn_mfma<<<512, 512, 0, stream>>>(q, KV, attn_out);

  // out = attn_out @ Wp + bp -> f32 d_out
  k_gemm_f32<<<dim3(4, 8, 8), 256, 0, stream>>>(attn_out, (long long)1024 * 512,
                                                wt_s + 6 * 262144 + 524288, bp,
                                                out, (long long)1024 * 512,
                                                1024, 512, 512);
  (void)in_sizes; (void)n_in; (void)out_size; (void)ws_size;
}